// Round 8
// baseline (2585.283 us; speedup 1.0000x reference)
//
#include <hip/hip_runtime.h>
#include <hip/hip_bf16.h>

typedef _Float16 f16;
typedef __attribute__((ext_vector_type(8))) _Float16 f16x8;
typedef __attribute__((ext_vector_type(2))) _Float16 f16x2;
typedef __attribute__((ext_vector_type(4))) float f32x4;

constexpr int CB = 64, CP = 196, CH = 512, CV = 30000, CVP = 30080, CT = 20;
constexpr int NTILES = CVP / 128;  // 235 preds column tiles

__device__ __forceinline__ float sigf(float x) { return 1.f / (1.f + __expf(-x)); }

#if defined(__has_builtin)
#if __has_builtin(__builtin_amdgcn_fdot2)
#define HAVE_FDOT2 1
#endif
#endif

__device__ __forceinline__ f16x2 asf16x2(unsigned u) {
    union { unsigned x; f16x2 h; } c; c.x = u; return c.h;
}
__device__ __forceinline__ float dotp(f16x2 a, f16x2 b, float c) {
#ifdef HAVE_FDOT2
    return __builtin_amdgcn_fdot2(a, b, c, false);
#else
    return fmaf((float)a[0], (float)b[0], fmaf((float)a[1], (float)b[1], c));
#endif
}

// ---- relaxed agent-scope (sc1, L3-coherent) helpers
__device__ __forceinline__ unsigned ald_u(const unsigned* p) {
    return __hip_atomic_load(p, __ATOMIC_RELAXED, __HIP_MEMORY_SCOPE_AGENT);
}
__device__ __forceinline__ void ast_u(unsigned* p, unsigned v) {
    __hip_atomic_store(p, v, __ATOMIC_RELAXED, __HIP_MEMORY_SCOPE_AGENT);
}
__device__ __forceinline__ f16x8 ald_h8(const f16* p) {
    const unsigned* u = (const unsigned*)p;
    union { unsigned w[4]; f16x8 h; } r;
    r.w[0] = ald_u(u); r.w[1] = ald_u(u + 1);
    r.w[2] = ald_u(u + 2); r.w[3] = ald_u(u + 3);
    return r.h;
}

// consumer: wave0 lanes poll 64 producer slots in parallel; s_barrier releases
__device__ __forceinline__ void wait_slots64(const int* base, int target) {
    if (threadIdx.x < 64) {
        for (;;) {
            int v = __hip_atomic_load(base + threadIdx.x, __ATOMIC_RELAXED,
                                      __HIP_MEMORY_SCOPE_AGENT);
            if (__all(v >= target)) break;
            __builtin_amdgcn_s_sleep(4);
        }
    }
    __builtin_amdgcn_s_barrier();
    __builtin_amdgcn_sched_barrier(0);
}
// producer: __syncthreads drains vmcnt (sc1 stores complete at L3), then post
__device__ __forceinline__ void post_slot(int* slot, int val) {
    __syncthreads();
    if (threadIdx.x == 0)
        __hip_atomic_store(slot, val, __ATOMIC_RELAXED, __HIP_MEMORY_SCOPE_AGENT);
}

// ---------------------------------------------------------------------------
// mega convert/transpose/prep kernel (one-time prologue)
//   WdaT[kk][o][2]  : o in 0..1023 (att2 cols 0-511 = W_da, gate cols = W_fb)
//   Bp  [kk][c][2]  : c = 4*d + g  (gate g of h-dim d), K = [xawe(512); h(512)]
//   WihE_p[c][512]  : rows = permuted cols c for the embIH GEMM
// ---------------------------------------------------------------------------
__device__ __forceinline__ void cvt8(const float* __restrict__ s, f16* __restrict__ d) {
    float4 a = *(const float4*)s;
    float4 b = *(const float4*)(s + 4);
    f16x8 o;
    o[0] = (f16)a.x; o[1] = (f16)a.y; o[2] = (f16)a.z; o[3] = (f16)a.w;
    o[4] = (f16)b.x; o[5] = (f16)b.y; o[6] = (f16)b.z; o[7] = (f16)b.w;
    *(f16x8*)d = o;
}

__global__ __launch_bounds__(256) void k_mega(
    const float* __restrict__ enc, const float* __restrict__ W_ea,
    const float* __restrict__ W_da, const float* __restrict__ W_fb,
    const float* __restrict__ W_ih, const float* __restrict__ W_hh,
    const float* __restrict__ W_fc, const float* __restrict__ emb,
    const int* __restrict__ caps, const float* __restrict__ b_da,
    const float* __restrict__ b_fb, const float* __restrict__ b_ih,
    const float* __restrict__ b_hh,
    f16* __restrict__ enc_h, f16* __restrict__ Wea_h, f16* __restrict__ WdaT,
    f16* __restrict__ Bp, f16* __restrict__ WihE_p, f16* __restrict__ Wfc_h,
    f16* __restrict__ embg, float* __restrict__ bcat, float* __restrict__ bsum_p,
    int* __restrict__ gsync)
{
    constexpr long long E0 = 802816;            // enc cvt (12544*512/8)
    constexpr long long E1 = E0 + 32768;        // W_ea
    constexpr long long E2 = E1 + 1920000;      // W_fc
    constexpr long long E3 = E2 + 5120;         // Wfc pad zeros
    constexpr long long E4 = E3 + 81920;        // emb gather
    constexpr long long E5 = E4 + 65536;        // WdaT paired-K  (kk 256 x oq 256)
    constexpr long long E6 = E5 + 262144;       // Bp paired-K    (kk 512 x cq 512)
    constexpr long long E7 = E6 + 131072;       // WihE_p         (c 2048 x 64)
    constexpr long long E8 = E7 + 3072;         // biases
    constexpr long long TOT = E8 + 64;          // sdone zero

    for (long long id = (long long)blockIdx.x * 256 + threadIdx.x; id < TOT;
         id += (long long)gridDim.x * 256) {
        if (id < E0) {
            cvt8(enc + id * 8, enc_h + id * 8);
        } else if (id < E1) {
            long long c = id - E0; cvt8(W_ea + c * 8, Wea_h + c * 8);
        } else if (id < E2) {
            long long c = id - E1; cvt8(W_fc + c * 8, Wfc_h + c * 8);
        } else if (id < E3) {
            long long c = id - E2; f16x8 z = {};
            *(f16x8*)&Wfc_h[15360000 + c * 8] = z;
        } else if (id < E4) {
            long long c = id - E3; int m = (int)(c >> 6), j = (int)(c & 63);
            int tt = m >> 6, bb = m & 63;
            int row = caps[bb * 21 + tt];
            cvt8(emb + (size_t)row * 512 + j * 8, embg + (size_t)m * 512 + j * 8);
        } else if (id < E5) {
            long long c = id - E4;
            int kk = (int)(c >> 8), oq = (int)(c & 255), o0 = oq * 4;
            f16x8 o;
#pragma unroll
            for (int d = 0; d < 4; ++d) {
                int oo = o0 + d;
                const float* src = (oo < 512) ? (W_da + (size_t)oo * 512)
                                              : (W_fb + (size_t)(oo - 512) * 512);
                o[2 * d]     = (f16)src[2 * kk];
                o[2 * d + 1] = (f16)src[2 * kk + 1];
            }
            *(f16x8*)&WdaT[(size_t)kk * 2048 + oq * 8] = o;
        } else if (id < E6) {
            long long c = id - E5;
            int kk = (int)(c >> 9), cq = (int)(c & 511);
            f16x8 o;
#pragma unroll
            for (int g = 0; g < 4; ++g) {
                int r = g * 512 + cq;   // orig gate row
#pragma unroll
                for (int j = 0; j < 2; ++j) {
                    int k = 2 * kk + j;
                    float v = (k < 512) ? W_ih[(size_t)r * 1024 + 512 + k]
                                        : W_hh[(size_t)r * 512 + (k - 512)];
                    o[2 * g + j] = (f16)v;
                }
            }
            *(f16x8*)&Bp[(size_t)kk * 4096 + cq * 8] = o;
        } else if (id < E7) {
            long long c = id - E6;
            int cc = (int)(c >> 6), j8 = (int)(c & 63);
            int r = (cc & 3) * 512 + (cc >> 2);
            cvt8(W_ih + (size_t)r * 1024 + j8 * 8, WihE_p + (size_t)cc * 512 + j8 * 8);
        } else if (id < E8) {
            int i = (int)(id - E7);
            if (i < 512) bcat[i] = b_da[i];
            else if (i < 1024) bcat[i] = b_fb[i - 512];
            else {
                int cc = i - 1024;
                int r = (cc & 3) * 512 + (cc >> 2);
                bsum_p[cc] = b_ih[r] + b_hh[r];
            }
        } else {
            gsync[(int)(id - E8)] = 0;
        }
    }
}

// h0 = mean_p(enc) -> hbuf slot 0 (f16) and cinit (f32)
__global__ __launch_bounds__(256) void k_h0(const float* __restrict__ enc,
                                            f16* __restrict__ hbuf, float* __restrict__ cinit)
{
    int b = blockIdx.x;
    for (int h = threadIdx.x; h < CH; h += 256) {
        const float* p = enc + (size_t)b * CP * CH + h;
        float s = 0.f;
        for (int q = 0; q < CP; ++q) s += p[q * CH];
        s *= (1.f / 196.f);
        hbuf[b * CH + h] = (f16)s;
        cinit[b * CH + h] = s;
    }
}

// ---------------------------------------------------------------------------
// K=512 GEMM (prologue): tile 128x128, BK=32, padded LDS, reg prefetch
// ---------------------------------------------------------------------------
enum { EPI_F16B = 0, EPI_F32B = 1 };

template <int EPI>
__global__ __launch_bounds__(256) void gemm_k512(
    const f16* __restrict__ Aptr, const f16* __restrict__ Bptr, int N,
    const float* __restrict__ bias, float* __restrict__ Cf, f16* __restrict__ Ch)
{
    constexpr int LD = 40;
    const int tid = threadIdx.x;
    const int lane = tid & 63, wave = tid >> 6;
    const int wr = wave >> 1, wc = wave & 1;
    const int bx = blockIdx.x, by = blockIdx.y;

    __shared__ f16 As[128 * LD];
    __shared__ f16 Bs[128 * LD];

    const f16* Ag = Aptr + (size_t)by * 128 * 512;
    const f16* Bg = Bptr + (size_t)bx * 128 * 512;

    int srow[2], skc[2];
#pragma unroll
    for (int i = 0; i < 2; ++i) { int ci = tid + i * 256; srow[i] = ci >> 2; skc[i] = (ci & 3) * 8; }

    f32x4 acc[4][4] = {};
    f16x8 ar[2], br[2];
#pragma unroll
    for (int i = 0; i < 2; ++i) {
        ar[i] = *(const f16x8*)&Ag[(size_t)srow[i] * 512 + skc[i]];
        br[i] = *(const f16x8*)&Bg[(size_t)srow[i] * 512 + skc[i]];
    }

    const int rr = lane & 15, kg = (lane >> 4) * 8;
    for (int kt = 0; kt < 16; ++kt) {
        __syncthreads();
#pragma unroll
        for (int i = 0; i < 2; ++i) {
            *(f16x8*)&As[srow[i] * LD + skc[i]] = ar[i];
            *(f16x8*)&Bs[srow[i] * LD + skc[i]] = br[i];
        }
        __syncthreads();
        if (kt < 15) {
            int k0 = (kt + 1) * 32;
#pragma unroll
            for (int i = 0; i < 2; ++i) {
                ar[i] = *(const f16x8*)&Ag[(size_t)srow[i] * 512 + k0 + skc[i]];
                br[i] = *(const f16x8*)&Bg[(size_t)srow[i] * 512 + k0 + skc[i]];
            }
        }
        f16x8 af[4], bf[4];
#pragma unroll
        for (int mi = 0; mi < 4; ++mi) af[mi] = *(const f16x8*)&As[(wr * 64 + mi * 16 + rr) * LD + kg];
#pragma unroll
        for (int ni = 0; ni < 4; ++ni) bf[ni] = *(const f16x8*)&Bs[(wc * 64 + ni * 16 + rr) * LD + kg];
#pragma unroll
        for (int mi = 0; mi < 4; ++mi)
#pragma unroll
            for (int ni = 0; ni < 4; ++ni)
                acc[mi][ni] = __builtin_amdgcn_mfma_f32_16x16x32_f16(af[mi], bf[ni], acc[mi][ni], 0, 0, 0);
    }

    const int m0 = by * 128 + wr * 64;
    const int n0 = bx * 128 + wc * 64;
    const int r0 = (lane >> 4) * 4, cc = lane & 15;
#pragma unroll
    for (int mi = 0; mi < 4; ++mi) {
#pragma unroll
        for (int ni = 0; ni < 4; ++ni) {
#pragma unroll
            for (int r = 0; r < 4; ++r) {
                int m = m0 + mi * 16 + r0 + r;
                int n = n0 + ni * 16 + cc;
                float v = acc[mi][ni][r] + bias[n];
                if constexpr (EPI == EPI_F16B) Ch[(size_t)m * N + n] = (f16)v;
                else Cf[(size_t)m * N + n] = v;
            }
        }
    }
}

// ---------------------------------------------------------------------------
// Fused loop + preds kernel: 64 + 235 blocks x 512 threads.
// Blocks 0..63  : per-batch recurrence, all state in LDS, zero waits.
//                 Posts sdone[b]=t+1 after writing h_{t+1} to hbuf (sc1).
// Blocks 64..298: preds workers. Block owns W_fc col-tile ntile (L2-resident);
//                 per t waits all 64 sdone, stages A (64x512) via sc1 -> LDS,
//                 computes 64x128 MFMA tile, masked scatter to out.
// ---------------------------------------------------------------------------
__global__ __launch_bounds__(512) void k_fused(
    const f16* __restrict__ att1, const f16* __restrict__ ench,
    const f16* __restrict__ WdaT, const f16* __restrict__ Bp,
    const float* __restrict__ embIH, const float* __restrict__ Wfa,
    const float* __restrict__ bfa, const float* __restrict__ bcat,
    const int* __restrict__ lens, const float* __restrict__ cinit,
    f16* __restrict__ hbuf, float* __restrict__ alph,
    const f16* __restrict__ Wfc_h, const float* __restrict__ bfc,
    float* __restrict__ outp, int* __restrict__ sdone)
{
    const int bid = blockIdx.x, tid = threadIdx.x;
    const int lane = tid & 63, wv = tid >> 6;

    __shared__ __align__(16) char smem[66816];

    if (bid < 64) {
        // ==================== per-batch recurrence ====================
        const int b = bid;
        f16*   h_s  = (f16*)smem;               // [512]
        float* c_s  = (float*)(smem + 1024);    // [512]
        f16*   a2_s = (f16*)(smem + 3072);      // [1024]
        f16*   xh_s = (f16*)(smem + 5120);      // [1024]
        float* es   = (float*)(smem + 7168);    // [200]
        float* als  = (float*)(smem + 7968);    // [200]
        float* red  = (float*)(smem + 8768);    // [16]
        float* awp  = (float*)(smem + 8832);    // [8][512]

        h_s[tid] = hbuf[b * 512 + tid];
        c_s[tid] = cinit[b * 512 + tid];

        const float bfa0 = bfa[0];
        const int lb = lens[b];
        const float bc0 = bcat[2 * tid], bc1 = bcat[2 * tid + 1];
        f16x2 wf2[4];
#pragma unroll
        for (int j = 0; j < 4; ++j) {
            float2 w2 = *(const float2*)&Wfa[lane * 8 + 2 * j];
            wf2[j][0] = (f16)w2.x; wf2[j][1] = (f16)w2.y;
        }
        __syncthreads();

        for (int t = 0; t < CT; ++t) {
            // ---- stage 1: att2+gate matvec (2 outs/thread, dbuf 8-load groups) ----
            {
                float a0 = 0.f, a1 = 0.f;
                const f16* wbase = WdaT + 4 * tid;
                uint2 wA[8], wB[8];
#pragma unroll
                for (int u = 0; u < 8; ++u)
                    wA[u] = *(const uint2*)(wbase + (size_t)u * 2048);
                for (int kko = 0; kko < 32; kko += 2) {
                    const f16* wpB = wbase + (size_t)(kko + 1) * 8 * 2048;
#pragma unroll
                    for (int u = 0; u < 8; ++u)
                        wB[u] = *(const uint2*)(wpB + (size_t)u * 2048);
                    {
                        uint4 xa = *(const uint4*)&h_s[kko * 16];
                        uint4 xb = *(const uint4*)&h_s[kko * 16 + 8];
                        unsigned xw[8] = {xa.x, xa.y, xa.z, xa.w, xb.x, xb.y, xb.z, xb.w};
#pragma unroll
                        for (int u = 0; u < 8; ++u) {
                            f16x2 xp = asf16x2(xw[u]);
                            a0 = dotp(asf16x2(wA[u].x), xp, a0);
                            a1 = dotp(asf16x2(wA[u].y), xp, a1);
                        }
                    }
                    if (kko + 2 < 32) {
                        const f16* wpA = wbase + (size_t)(kko + 2) * 8 * 2048;
#pragma unroll
                        for (int u = 0; u < 8; ++u)
                            wA[u] = *(const uint2*)(wpA + (size_t)u * 2048);
                    }
                    {
                        uint4 xa = *(const uint4*)&h_s[(kko + 1) * 16];
                        uint4 xb = *(const uint4*)&h_s[(kko + 1) * 16 + 8];
                        unsigned xw[8] = {xa.x, xa.y, xa.z, xa.w, xb.x, xb.y, xb.z, xb.w};
#pragma unroll
                        for (int u = 0; u < 8; ++u) {
                            f16x2 xp = asf16x2(xw[u]);
                            a0 = dotp(asf16x2(wB[u].x), xp, a0);
                            a1 = dotp(asf16x2(wB[u].y), xp, a1);
                        }
                    }
                }
                f16x2 o; o[0] = (f16)(a0 + bc0); o[1] = (f16)(a1 + bc1);
                *(f16x2*)&a2_s[2 * tid] = o;
            }
            __syncthreads();

            // ---- stage 2: e[p] = Wfa . relu(att1[b,p,:] + att2) + bfa ----
            {
                uint4 a2v = *(const uint4*)&a2_s[lane * 8];
                unsigned a2w[4] = {a2v.x, a2v.y, a2v.z, a2v.w};
                for (int p = wv; p < CP; p += 8) {
                    uint4 av = *(const uint4*)&att1[((size_t)b * CP + p) * 512 + lane * 8];
                    unsigned aw4[4] = {av.x, av.y, av.z, av.w};
                    float eacc = 0.f;
#pragma unroll
                    for (int j = 0; j < 4; ++j) {
                        f16x2 s = asf16x2(aw4[j]) + asf16x2(a2w[j]);
                        f16x2 r;
                        r[0] = (s[0] < (f16)0) ? (f16)0 : s[0];
                        r[1] = (s[1] < (f16)0) ? (f16)0 : s[1];
                        eacc = dotp(r, wf2[j], eacc);
                    }
#pragma unroll
                    for (int o = 32; o; o >>= 1) eacc += __shfl_down(eacc, o);
                    if (lane == 0) es[p] = eacc + bfa0;
                }
            }
            __syncthreads();

            // ---- stage 3: softmax over 196 ----
            {
                float ev = (tid < CP) ? es[tid] : -1e30f;
                float mx = ev;
#pragma unroll
                for (int o = 32; o; o >>= 1) mx = fmaxf(mx, __shfl_down(mx, o));
                if (lane == 0) red[wv] = mx;
                __syncthreads();
                mx = red[0];
#pragma unroll
                for (int w = 1; w < 8; ++w) mx = fmaxf(mx, red[w]);
                float ex = (tid < CP) ? __expf(ev - mx) : 0.f;
                float sm = ex;
#pragma unroll
                for (int o = 32; o; o >>= 1) sm += __shfl_down(sm, o);
                if (lane == 0) red[8 + wv] = sm;
                __syncthreads();
                sm = red[8];
#pragma unroll
                for (int w = 1; w < 8; ++w) sm += red[8 + w];
                float al = ex / sm;
                if (tid < CP) {
                    als[tid] = al;
                    alph[(size_t)b * (CT * CP) + t * CP + tid] = ((lb - 1) > t) ? al : 0.f;
                }
            }
            __syncthreads();

            // ---- stage 4: awe + gate + xh ----
            {
                float aw[8] = {};
                for (int p = wv; p < CP; p += 8) {
                    float a = als[p];
                    uint4 ev = *(const uint4*)&ench[((size_t)b * CP + p) * 512 + lane * 8];
                    unsigned ew[4] = {ev.x, ev.y, ev.z, ev.w};
#pragma unroll
                    for (int j = 0; j < 4; ++j) {
                        f16x2 e2 = asf16x2(ew[j]);
                        aw[2 * j]     = fmaf(a, (float)e2[0], aw[2 * j]);
                        aw[2 * j + 1] = fmaf(a, (float)e2[1], aw[2 * j + 1]);
                    }
                }
#pragma unroll
                for (int j = 0; j < 8; ++j) awp[wv * 512 + lane * 8 + j] = aw[j];
                __syncthreads();
                float s = 0.f;
#pragma unroll
                for (int w = 0; w < 8; ++w) s += awp[w * 512 + tid];
                float gate = sigf((float)a2_s[512 + tid]);
                xh_s[tid] = (f16)(gate * s);
                xh_s[512 + tid] = h_s[tid];
            }
            __syncthreads();

            // ---- stage 5: gates matvec (4 outs/thread, dbuf 8-load groups) + cell ----
            float cn, hn;
            {
                float g0 = 0.f, g1 = 0.f, g2 = 0.f, g3 = 0.f;
                const f16* wbase = Bp + 8 * tid;
                uint4 wA[8], wB[8];
#pragma unroll
                for (int u = 0; u < 8; ++u)
                    wA[u] = *(const uint4*)(wbase + (size_t)u * 4096);
                for (int kko = 0; kko < 64; kko += 2) {
                    const f16* wpB = wbase + (size_t)(kko + 1) * 8 * 4096;
#pragma unroll
                    for (int u = 0; u < 8; ++u)
                        wB[u] = *(const uint4*)(wpB + (size_t)u * 4096);
                    {
                        uint4 xa = *(const uint4*)&xh_s[kko * 16];
                        uint4 xb = *(const uint4*)&xh_s[kko * 16 + 8];
                        unsigned xw[8] = {xa.x, xa.y, xa.z, xa.w, xb.x, xb.y, xb.z, xb.w};
#pragma unroll
                        for (int u = 0; u < 8; ++u) {
                            f16x2 xp = asf16x2(xw[u]);
                            g0 = dotp(asf16x2(wA[u].x), xp, g0);
                            g1 = dotp(asf16x2(wA[u].y), xp, g1);
                            g2 = dotp(asf16x2(wA[u].z), xp, g2);
                            g3 = dotp(asf16x2(wA[u].w), xp, g3);
                        }
                    }
                    if (kko + 2 < 64) {
                        const f16* wpA = wbase + (size_t)(kko + 2) * 8 * 4096;
#pragma unroll
                        for (int u = 0; u < 8; ++u)
                            wA[u] = *(const uint4*)(wpA + (size_t)u * 4096);
                    }
                    {
                        uint4 xa = *(const uint4*)&xh_s[(kko + 1) * 16];
                        uint4 xb = *(const uint4*)&xh_s[(kko + 1) * 16 + 8];
                        unsigned xw[8] = {xa.x, xa.y, xa.z, xa.w, xb.x, xb.y, xb.z, xb.w};
#pragma unroll
                        for (int u = 0; u < 8; ++u) {
                            f16x2 xp = asf16x2(xw[u]);
                            g0 = dotp(asf16x2(wB[u].x), xp, g0);
                            g1 = dotp(asf16x2(wB[u].y), xp, g1);
                            g2 = dotp(asf16x2(wB[u].z), xp, g2);
                            g3 = dotp(asf16x2(wB[u].w), xp, g3);
                        }
                    }
                }
                float4 ei = *(const float4*)&embIH[(size_t)(t * 64 + b) * 2048 + 4 * tid];
                float gi = g0 + ei.x, gf = g1 + ei.y, gg = g2 + ei.z, go = g3 + ei.w;
                cn = sigf(gf) * c_s[tid] + sigf(gi) * tanhf(gg);
                hn = sigf(go) * tanhf(cn);
            }
            __syncthreads();   // readers of old h_s/xh_s/c_s done
            c_s[tid] = cn;
            h_s[tid] = (f16)hn;
            __syncthreads();   // h_s complete
            if (tid < 256)
                ast_u((unsigned*)&hbuf[(size_t)(t + 1) * 32768 + b * 512] + tid,
                      *((unsigned*)h_s + tid));
            post_slot(&sdone[b], t + 1);   // syncthreads + flag
        }
    } else {
        // ==================== preds worker ====================
        const int ntile = bid - 64;
        f16* As = (f16*)smem;                         // [64][520]
        const f16* Bt = Wfc_h + (size_t)ntile * 128 * 512;
        const int rr = lane & 15, kg = (lane >> 4) * 8;
        const int wr = wv >> 2, wc = wv & 3;
        const int r0 = (lane >> 4) * 4, ccl = lane & 15;

        for (int t = 0; t < CT; ++t) {
            wait_slots64(sdone, t + 1);
            const f16* Ag = hbuf + (size_t)(t + 1) * 32768;
            for (int ch = tid; ch < 4096; ch += 512) {
                int row = ch >> 6, kc = (ch & 63) * 8;
                f16x8 v = ald_h8(&Ag[row * 512 + kc]);
                *(f16x8*)&As[row * 520 + kc] = v;
            }
            __syncthreads();

            f32x4 acc[2][2] = {};
#pragma unroll 4
            for (int k0 = 0; k0 < 512; k0 += 32) {
                f16x8 bf[2];
#pragma unroll
                for (int ni = 0; ni < 2; ++ni)
                    bf[ni] = *(const f16x8*)&Bt[(size_t)(wc * 32 + ni * 16 + rr) * 512 + k0 + kg];
#pragma unroll
                for (int mi = 0; mi < 2; ++mi) {
                    f16x8 af = *(const f16x8*)&As[(wr * 32 + mi * 16 + rr) * 520 + k0 + kg];
#pragma unroll
                    for (int ni = 0; ni < 2; ++ni)
                        acc[mi][ni] = __builtin_amdgcn_mfma_f32_16x16x32_f16(af, bf[ni], acc[mi][ni], 0, 0, 0);
                }
            }
#pragma unroll
            for (int mi = 0; mi < 2; ++mi) {
#pragma unroll
                for (int ni = 0; ni < 2; ++ni) {
#pragma unroll
                    for (int r = 0; r < 4; ++r) {
                        int m = wr * 32 + mi * 16 + r0 + r;             // batch
                        int n = ntile * 128 + wc * 32 + ni * 16 + ccl;  // vocab
                        if (n < CV) {
                            float val = ((lens[m] - 1) > t) ? (acc[mi][ni][r] + bfc[n]) : 0.f;
                            __builtin_nontemporal_store(val,
                                &outp[(size_t)m * (CT * CV) + (size_t)t * CV + n]);
                        }
                    }
                }
            }
            __syncthreads();   // done with As before next t overwrites
        }
    }
}

// ---------------------------------------------------------------------------
extern "C" void kernel_launch(void* const* d_in, const int* in_sizes, int n_in,
                              void* d_out, int out_size, void* d_ws, size_t ws_size,
                              hipStream_t stream)
{
    const float* enc  = (const float*)d_in[0];
    const int*   caps = (const int*)d_in[1];
    const int*   lens = (const int*)d_in[2];
    const float* emb  = (const float*)d_in[3];
    const float* W_ea = (const float*)d_in[4];
    const float* b_ea = (const float*)d_in[5];
    const float* W_da = (const float*)d_in[6];
    const float* b_da = (const float*)d_in[7];
    const float* W_fa = (const float*)d_in[8];
    const float* b_fa = (const float*)d_in[9];
    const float* W_fb = (const float*)d_in[10];
    const float* b_fb = (const float*)d_in[11];
    const float* W_ih = (const float*)d_in[12];
    const float* W_hh = (const float*)d_in[13];
    const float* b_ih = (const float*)d_in[14];
    const float* b_hh = (const float*)d_in[15];
    const float* W_fc = (const float*)d_in[16];
    const float* b_fc = (const float*)d_in[17];

    float* out = (float*)d_out;
    float* alph_out = out + (size_t)CB * CT * CV;

    char* p = (char*)d_ws;
    auto carve = [&](size_t bytes) {
        char* r = p;
        p += (bytes + 255) & ~(size_t)255;
        return r;
    };
    f16* enc_h   = (f16*)carve((size_t)12544 * 512 * 2);
    f16* att1_h  = (f16*)carve((size_t)12544 * 512 * 2);
    f16* Wea_h   = (f16*)carve((size_t)512 * 512 * 2);
    f16* WdaT    = (f16*)carve((size_t)256 * 1024 * 2 * 2);   // [kk][1024][2]
    f16* Bp      = (f16*)carve((size_t)512 * 2048 * 2 * 2);   // [kk][2048][2]
    f16* WihE_p  = (f16*)carve((size_t)2048 * 512 * 2);
    f16* Wfc_h   = (f16*)carve((size_t)CVP * 512 * 2);
    f16* embg    = (f16*)carve((size_t)1280 * 512 * 2);
    float* embIH = (float*)carve((size_t)1280 * 2048 * 4);
    float* bcat  = (float*)carve(1024 * 4);
    float* bsum_p= (float*)carve(2048 * 4);
    f16* hbuf    = (f16*)carve((size_t)21 * 64 * 512 * 2);
    float* cinit = (float*)carve((size_t)64 * 512 * 4);
    int* gsync   = (int*)carve(4096);

    hipLaunchKernelGGL(k_mega, dim3(4096), dim3(256), 0, stream,
                       enc, W_ea, W_da, W_fb, W_ih, W_hh, W_fc, emb, caps,
                       b_da, b_fb, b_ih, b_hh,
                       enc_h, Wea_h, WdaT, Bp, WihE_p, Wfc_h, embg, bcat, bsum_p, gsync);

    hipLaunchKernelGGL(k_h0, dim3(64), dim3(256), 0, stream, enc, hbuf, cinit);

    // att1 = enc_h @ W_ea^T + b_ea  (M=12544, N=512) -> f16
    hipLaunchKernelGGL((gemm_k512<EPI_F16B>), dim3(4, 98), dim3(256), 0, stream,
                       enc_h, Wea_h, 512, b_ea, (float*)nullptr, att1_h);
    // embIH = embg @ WihE_p^T + bsum_p  (M=1280, N=2048 permuted c=4d+g) -> f32
    hipLaunchKernelGGL((gemm_k512<EPI_F32B>), dim3(16, 10), dim3(256), 0, stream,
                       embg, WihE_p, 2048, bsum_p, embIH, (f16*)nullptr);

    // fused: 64 per-batch recurrence blocks + 235 overlapped preds blocks
    hipLaunchKernelGGL(k_fused, dim3(64 + NTILES), dim3(512), 0, stream,
                       att1_h, enc_h, WdaT, Bp, embIH, W_fa, b_fa, bcat,
                       lens, cinit, hbuf, alph_out, Wfc_h, b_fc, out, gsync);
}

// Round 9
// 2584.664 us; speedup vs baseline: 1.0002x; 1.0002x over previous
//
#include <hip/hip_runtime.h>
#include <hip/hip_bf16.h>

typedef _Float16 f16;
typedef __attribute__((ext_vector_type(8))) _Float16 f16x8;
typedef __attribute__((ext_vector_type(2))) _Float16 f16x2;
typedef __attribute__((ext_vector_type(4))) float f32x4;

constexpr int CB = 64, CP = 196, CH = 512, CV = 30000, CVP = 30080, CT = 20;
constexpr int NTILES = CVP / 128;  // 235 preds column tiles

__device__ __forceinline__ float sigf(float x) { return 1.f / (1.f + __expf(-x)); }

#if defined(__has_builtin)
#if __has_builtin(__builtin_amdgcn_fdot2)
#define HAVE_FDOT2 1
#endif
#endif

__device__ __forceinline__ f16x2 asf16x2(unsigned u) {
    union { unsigned x; f16x2 h; } c; c.x = u; return c.h;
}
__device__ __forceinline__ float dotp(f16x2 a, f16x2 b, float c) {
#ifdef HAVE_FDOT2
    return __builtin_amdgcn_fdot2(a, b, c, false);
#else
    return fmaf((float)a[0], (float)b[0], fmaf((float)a[1], (float)b[1], c));
#endif
}

// ---- relaxed agent-scope (sc1, L3-coherent) helpers
__device__ __forceinline__ unsigned ald_u(const unsigned* p) {
    return __hip_atomic_load(p, __ATOMIC_RELAXED, __HIP_MEMORY_SCOPE_AGENT);
}
__device__ __forceinline__ void ast_u(unsigned* p, unsigned v) {
    __hip_atomic_store(p, v, __ATOMIC_RELAXED, __HIP_MEMORY_SCOPE_AGENT);
}
__device__ __forceinline__ f16x8 ald_h8(const f16* p) {
    const unsigned* u = (const unsigned*)p;
    union { unsigned w[4]; f16x8 h; } r;
    r.w[0] = ald_u(u); r.w[1] = ald_u(u + 1);
    r.w[2] = ald_u(u + 2); r.w[3] = ald_u(u + 3);
    return r.h;
}

// consumer: wave0 lanes poll 64 producer slots in parallel; s_barrier releases
__device__ __forceinline__ void wait_slots64(const int* base, int target) {
    if (threadIdx.x < 64) {
        for (;;) {
            int v = __hip_atomic_load(base + threadIdx.x, __ATOMIC_RELAXED,
                                      __HIP_MEMORY_SCOPE_AGENT);
            if (__all(v >= target)) break;
            __builtin_amdgcn_s_sleep(4);
        }
    }
    __builtin_amdgcn_s_barrier();
    __builtin_amdgcn_sched_barrier(0);
}
// producer: __syncthreads drains vmcnt (sc1 stores complete at L3), then post
__device__ __forceinline__ void post_slot(int* slot, int val) {
    __syncthreads();
    if (threadIdx.x == 0)
        __hip_atomic_store(slot, val, __ATOMIC_RELAXED, __HIP_MEMORY_SCOPE_AGENT);
}

// ---------------------------------------------------------------------------
// mega convert/transpose/prep kernel (one-time prologue)
//   WdaT[kk][o][2]  : o in 0..1023 (att2 cols 0-511 = W_da, gate cols = W_fb)
//   Bp  [kk][c][2]  : c = 4*d + g  (gate g of h-dim d), K = [xawe(512); h(512)]
//   WihE_p[c][512]  : rows = permuted cols c for the embIH GEMM
// ---------------------------------------------------------------------------
__device__ __forceinline__ void cvt8(const float* __restrict__ s, f16* __restrict__ d) {
    float4 a = *(const float4*)s;
    float4 b = *(const float4*)(s + 4);
    f16x8 o;
    o[0] = (f16)a.x; o[1] = (f16)a.y; o[2] = (f16)a.z; o[3] = (f16)a.w;
    o[4] = (f16)b.x; o[5] = (f16)b.y; o[6] = (f16)b.z; o[7] = (f16)b.w;
    *(f16x8*)d = o;
}

__global__ __launch_bounds__(256) void k_mega(
    const float* __restrict__ enc, const float* __restrict__ W_ea,
    const float* __restrict__ W_da, const float* __restrict__ W_fb,
    const float* __restrict__ W_ih, const float* __restrict__ W_hh,
    const float* __restrict__ W_fc, const float* __restrict__ emb,
    const int* __restrict__ caps, const float* __restrict__ b_da,
    const float* __restrict__ b_fb, const float* __restrict__ b_ih,
    const float* __restrict__ b_hh,
    f16* __restrict__ enc_h, f16* __restrict__ Wea_h, f16* __restrict__ WdaT,
    f16* __restrict__ Bp, f16* __restrict__ WihE_p, f16* __restrict__ Wfc_h,
    f16* __restrict__ embg, float* __restrict__ bcat, float* __restrict__ bsum_p,
    int* __restrict__ gsync)
{
    constexpr long long E0 = 802816;            // enc cvt (12544*512/8)
    constexpr long long E1 = E0 + 32768;        // W_ea
    constexpr long long E2 = E1 + 1920000;      // W_fc
    constexpr long long E3 = E2 + 5120;         // Wfc pad zeros
    constexpr long long E4 = E3 + 81920;        // emb gather
    constexpr long long E5 = E4 + 65536;        // WdaT paired-K  (kk 256 x oq 256)
    constexpr long long E6 = E5 + 262144;       // Bp paired-K    (kk 512 x cq 512)
    constexpr long long E7 = E6 + 131072;       // WihE_p         (c 2048 x 64)
    constexpr long long E8 = E7 + 3072;         // biases
    constexpr long long TOT = E8 + 64;          // sdone zero

    for (long long id = (long long)blockIdx.x * 256 + threadIdx.x; id < TOT;
         id += (long long)gridDim.x * 256) {
        if (id < E0) {
            cvt8(enc + id * 8, enc_h + id * 8);
        } else if (id < E1) {
            long long c = id - E0; cvt8(W_ea + c * 8, Wea_h + c * 8);
        } else if (id < E2) {
            long long c = id - E1; cvt8(W_fc + c * 8, Wfc_h + c * 8);
        } else if (id < E3) {
            long long c = id - E2; f16x8 z = {};
            *(f16x8*)&Wfc_h[15360000 + c * 8] = z;
        } else if (id < E4) {
            long long c = id - E3; int m = (int)(c >> 6), j = (int)(c & 63);
            int tt = m >> 6, bb = m & 63;
            int row = caps[bb * 21 + tt];
            cvt8(emb + (size_t)row * 512 + j * 8, embg + (size_t)m * 512 + j * 8);
        } else if (id < E5) {
            long long c = id - E4;
            int kk = (int)(c >> 8), oq = (int)(c & 255), o0 = oq * 4;
            f16x8 o;
#pragma unroll
            for (int d = 0; d < 4; ++d) {
                int oo = o0 + d;
                const float* src = (oo < 512) ? (W_da + (size_t)oo * 512)
                                              : (W_fb + (size_t)(oo - 512) * 512);
                o[2 * d]     = (f16)src[2 * kk];
                o[2 * d + 1] = (f16)src[2 * kk + 1];
            }
            *(f16x8*)&WdaT[(size_t)kk * 2048 + oq * 8] = o;
        } else if (id < E6) {
            long long c = id - E5;
            int kk = (int)(c >> 9), cq = (int)(c & 511);
            f16x8 o;
#pragma unroll
            for (int g = 0; g < 4; ++g) {
                int r = g * 512 + cq;   // orig gate row
#pragma unroll
                for (int j = 0; j < 2; ++j) {
                    int k = 2 * kk + j;
                    float v = (k < 512) ? W_ih[(size_t)r * 1024 + 512 + k]
                                        : W_hh[(size_t)r * 512 + (k - 512)];
                    o[2 * g + j] = (f16)v;
                }
            }
            *(f16x8*)&Bp[(size_t)kk * 4096 + cq * 8] = o;
        } else if (id < E7) {
            long long c = id - E6;
            int cc = (int)(c >> 6), j8 = (int)(c & 63);
            int r = (cc & 3) * 512 + (cc >> 2);
            cvt8(W_ih + (size_t)r * 1024 + j8 * 8, WihE_p + (size_t)cc * 512 + j8 * 8);
        } else if (id < E8) {
            int i = (int)(id - E7);
            if (i < 512) bcat[i] = b_da[i];
            else if (i < 1024) bcat[i] = b_fb[i - 512];
            else {
                int cc = i - 1024;
                int r = (cc & 3) * 512 + (cc >> 2);
                bsum_p[cc] = b_ih[r] + b_hh[r];
            }
        } else {
            gsync[(int)(id - E8)] = 0;
        }
    }
}

// h0 = mean_p(enc) -> hbuf slot 0 (f16) and cinit (f32)
__global__ __launch_bounds__(256) void k_h0(const float* __restrict__ enc,
                                            f16* __restrict__ hbuf, float* __restrict__ cinit)
{
    int b = blockIdx.x;
    for (int h = threadIdx.x; h < CH; h += 256) {
        const float* p = enc + (size_t)b * CP * CH + h;
        float s = 0.f;
        for (int q = 0; q < CP; ++q) s += p[q * CH];
        s *= (1.f / 196.f);
        hbuf[b * CH + h] = (f16)s;
        cinit[b * CH + h] = s;
    }
}

// ---------------------------------------------------------------------------
// K=512 GEMM (prologue): tile 128x128, BK=32, padded LDS, reg prefetch
// ---------------------------------------------------------------------------
enum { EPI_F16B = 0, EPI_F32B = 1 };

template <int EPI>
__global__ __launch_bounds__(256) void gemm_k512(
    const f16* __restrict__ Aptr, const f16* __restrict__ Bptr, int N,
    const float* __restrict__ bias, float* __restrict__ Cf, f16* __restrict__ Ch)
{
    constexpr int LD = 40;
    const int tid = threadIdx.x;
    const int lane = tid & 63, wave = tid >> 6;
    const int wr = wave >> 1, wc = wave & 1;
    const int bx = blockIdx.x, by = blockIdx.y;

    __shared__ f16 As[128 * LD];
    __shared__ f16 Bs[128 * LD];

    const f16* Ag = Aptr + (size_t)by * 128 * 512;
    const f16* Bg = Bptr + (size_t)bx * 128 * 512;

    int srow[2], skc[2];
#pragma unroll
    for (int i = 0; i < 2; ++i) { int ci = tid + i * 256; srow[i] = ci >> 2; skc[i] = (ci & 3) * 8; }

    f32x4 acc[4][4] = {};
    f16x8 ar[2], br[2];
#pragma unroll
    for (int i = 0; i < 2; ++i) {
        ar[i] = *(const f16x8*)&Ag[(size_t)srow[i] * 512 + skc[i]];
        br[i] = *(const f16x8*)&Bg[(size_t)srow[i] * 512 + skc[i]];
    }

    const int rr = lane & 15, kg = (lane >> 4) * 8;
    for (int kt = 0; kt < 16; ++kt) {
        __syncthreads();
#pragma unroll
        for (int i = 0; i < 2; ++i) {
            *(f16x8*)&As[srow[i] * LD + skc[i]] = ar[i];
            *(f16x8*)&Bs[srow[i] * LD + skc[i]] = br[i];
        }
        __syncthreads();
        if (kt < 15) {
            int k0 = (kt + 1) * 32;
#pragma unroll
            for (int i = 0; i < 2; ++i) {
                ar[i] = *(const f16x8*)&Ag[(size_t)srow[i] * 512 + k0 + skc[i]];
                br[i] = *(const f16x8*)&Bg[(size_t)srow[i] * 512 + k0 + skc[i]];
            }
        }
        f16x8 af[4], bf[4];
#pragma unroll
        for (int mi = 0; mi < 4; ++mi) af[mi] = *(const f16x8*)&As[(wr * 64 + mi * 16 + rr) * LD + kg];
#pragma unroll
        for (int ni = 0; ni < 4; ++ni) bf[ni] = *(const f16x8*)&Bs[(wc * 64 + ni * 16 + rr) * LD + kg];
#pragma unroll
        for (int mi = 0; mi < 4; ++mi)
#pragma unroll
            for (int ni = 0; ni < 4; ++ni)
                acc[mi][ni] = __builtin_amdgcn_mfma_f32_16x16x32_f16(af[mi], bf[ni], acc[mi][ni], 0, 0, 0);
    }

    const int m0 = by * 128 + wr * 64;
    const int n0 = bx * 128 + wc * 64;
    const int r0 = (lane >> 4) * 4, cc = lane & 15;
#pragma unroll
    for (int mi = 0; mi < 4; ++mi) {
#pragma unroll
        for (int ni = 0; ni < 4; ++ni) {
#pragma unroll
            for (int r = 0; r < 4; ++r) {
                int m = m0 + mi * 16 + r0 + r;
                int n = n0 + ni * 16 + cc;
                float v = acc[mi][ni][r] + bias[n];
                if constexpr (EPI == EPI_F16B) Ch[(size_t)m * N + n] = (f16)v;
                else Cf[(size_t)m * N + n] = v;
            }
        }
    }
}

// ---------------------------------------------------------------------------
// Fused loop + preds kernel: 64 + 235 blocks x 512 threads.
// Blocks 0..63  : per-batch recurrence, all state in LDS, zero waits.
//                 Posts sdone[b]=t+1 after writing h_{t+1} to hbuf (sc1).
// Blocks 64..298: preds workers. Block owns W_fc col-tile ntile (L2-resident);
//                 per t waits all 64 sdone, stages A (64x512) via sc1 -> LDS,
//                 computes 64x128 MFMA tile, masked scatter to out.
// ---------------------------------------------------------------------------
__global__ __launch_bounds__(512) void k_fused(
    const f16* __restrict__ att1, const f16* __restrict__ ench,
    const f16* __restrict__ WdaT, const f16* __restrict__ Bp,
    const float* __restrict__ embIH, const float* __restrict__ Wfa,
    const float* __restrict__ bfa, const float* __restrict__ bcat,
    const int* __restrict__ lens, const float* __restrict__ cinit,
    f16* __restrict__ hbuf, float* __restrict__ alph,
    const f16* __restrict__ Wfc_h, const float* __restrict__ bfc,
    float* __restrict__ outp, int* __restrict__ sdone)
{
    const int bid = blockIdx.x, tid = threadIdx.x;
    const int lane = tid & 63, wv = tid >> 6;

    __shared__ __align__(16) char smem[66816];

    if (bid < 64) {
        // ==================== per-batch recurrence ====================
        const int b = bid;
        f16*   h_s  = (f16*)smem;               // [512]
        float* c_s  = (float*)(smem + 1024);    // [512]
        f16*   a2_s = (f16*)(smem + 3072);      // [1024]
        f16*   xh_s = (f16*)(smem + 5120);      // [1024]
        float* es   = (float*)(smem + 7168);    // [200]
        float* als  = (float*)(smem + 7968);    // [200]
        float* red  = (float*)(smem + 8768);    // [16]
        float* awp  = (float*)(smem + 8832);    // [8][512]

        h_s[tid] = hbuf[b * 512 + tid];
        c_s[tid] = cinit[b * 512 + tid];

        const float bfa0 = bfa[0];
        const int lb = lens[b];
        const float bc0 = bcat[2 * tid], bc1 = bcat[2 * tid + 1];
        f16x2 wf2[4];
#pragma unroll
        for (int j = 0; j < 4; ++j) {
            float2 w2 = *(const float2*)&Wfa[lane * 8 + 2 * j];
            wf2[j][0] = (f16)w2.x; wf2[j][1] = (f16)w2.y;
        }
        __syncthreads();

        for (int t = 0; t < CT; ++t) {
            // ---- stage 1: att2+gate matvec (2 outs/thread, dbuf 8-load groups) ----
            {
                float a0 = 0.f, a1 = 0.f;
                const f16* wbase = WdaT + 4 * tid;
                uint2 wA[8], wB[8];
#pragma unroll
                for (int u = 0; u < 8; ++u)
                    wA[u] = *(const uint2*)(wbase + (size_t)u * 2048);
                for (int kko = 0; kko < 32; kko += 2) {
                    const f16* wpB = wbase + (size_t)(kko + 1) * 8 * 2048;
#pragma unroll
                    for (int u = 0; u < 8; ++u)
                        wB[u] = *(const uint2*)(wpB + (size_t)u * 2048);
                    {
                        uint4 xa = *(const uint4*)&h_s[kko * 16];
                        uint4 xb = *(const uint4*)&h_s[kko * 16 + 8];
                        unsigned xw[8] = {xa.x, xa.y, xa.z, xa.w, xb.x, xb.y, xb.z, xb.w};
#pragma unroll
                        for (int u = 0; u < 8; ++u) {
                            f16x2 xp = asf16x2(xw[u]);
                            a0 = dotp(asf16x2(wA[u].x), xp, a0);
                            a1 = dotp(asf16x2(wA[u].y), xp, a1);
                        }
                    }
                    if (kko + 2 < 32) {
                        const f16* wpA = wbase + (size_t)(kko + 2) * 8 * 2048;
#pragma unroll
                        for (int u = 0; u < 8; ++u)
                            wA[u] = *(const uint2*)(wpA + (size_t)u * 2048);
                    }
                    {
                        uint4 xa = *(const uint4*)&h_s[(kko + 1) * 16];
                        uint4 xb = *(const uint4*)&h_s[(kko + 1) * 16 + 8];
                        unsigned xw[8] = {xa.x, xa.y, xa.z, xa.w, xb.x, xb.y, xb.z, xb.w};
#pragma unroll
                        for (int u = 0; u < 8; ++u) {
                            f16x2 xp = asf16x2(xw[u]);
                            a0 = dotp(asf16x2(wB[u].x), xp, a0);
                            a1 = dotp(asf16x2(wB[u].y), xp, a1);
                        }
                    }
                }
                f16x2 o; o[0] = (f16)(a0 + bc0); o[1] = (f16)(a1 + bc1);
                *(f16x2*)&a2_s[2 * tid] = o;
            }
            __syncthreads();

            // ---- stage 2: e[p] = Wfa . relu(att1[b,p,:] + att2) + bfa ----
            {
                uint4 a2v = *(const uint4*)&a2_s[lane * 8];
                unsigned a2w[4] = {a2v.x, a2v.y, a2v.z, a2v.w};
                for (int p = wv; p < CP; p += 8) {
                    uint4 av = *(const uint4*)&att1[((size_t)b * CP + p) * 512 + lane * 8];
                    unsigned aw4[4] = {av.x, av.y, av.z, av.w};
                    float eacc = 0.f;
#pragma unroll
                    for (int j = 0; j < 4; ++j) {
                        f16x2 s = asf16x2(aw4[j]) + asf16x2(a2w[j]);
                        f16x2 r;
                        r[0] = (s[0] < (f16)0) ? (f16)0 : s[0];
                        r[1] = (s[1] < (f16)0) ? (f16)0 : s[1];
                        eacc = dotp(r, wf2[j], eacc);
                    }
#pragma unroll
                    for (int o = 32; o; o >>= 1) eacc += __shfl_down(eacc, o);
                    if (lane == 0) es[p] = eacc + bfa0;
                }
            }
            __syncthreads();

            // ---- stage 3: softmax over 196 ----
            {
                float ev = (tid < CP) ? es[tid] : -1e30f;
                float mx = ev;
#pragma unroll
                for (int o = 32; o; o >>= 1) mx = fmaxf(mx, __shfl_down(mx, o));
                if (lane == 0) red[wv] = mx;
                __syncthreads();
                mx = red[0];
#pragma unroll
                for (int w = 1; w < 8; ++w) mx = fmaxf(mx, red[w]);
                float ex = (tid < CP) ? __expf(ev - mx) : 0.f;
                float sm = ex;
#pragma unroll
                for (int o = 32; o; o >>= 1) sm += __shfl_down(sm, o);
                if (lane == 0) red[8 + wv] = sm;
                __syncthreads();
                sm = red[8];
#pragma unroll
                for (int w = 1; w < 8; ++w) sm += red[8 + w];
                float al = ex / sm;
                if (tid < CP) {
                    als[tid] = al;
                    alph[(size_t)b * (CT * CP) + t * CP + tid] = ((lb - 1) > t) ? al : 0.f;
                }
            }
            __syncthreads();

            // ---- stage 4: awe + gate + xh ----
            {
                float aw[8] = {};
                for (int p = wv; p < CP; p += 8) {
                    float a = als[p];
                    uint4 ev = *(const uint4*)&ench[((size_t)b * CP + p) * 512 + lane * 8];
                    unsigned ew[4] = {ev.x, ev.y, ev.z, ev.w};
#pragma unroll
                    for (int j = 0; j < 4; ++j) {
                        f16x2 e2 = asf16x2(ew[j]);
                        aw[2 * j]     = fmaf(a, (float)e2[0], aw[2 * j]);
                        aw[2 * j + 1] = fmaf(a, (float)e2[1], aw[2 * j + 1]);
                    }
                }
#pragma unroll
                for (int j = 0; j < 8; ++j) awp[wv * 512 + lane * 8 + j] = aw[j];
                __syncthreads();
                float s = 0.f;
#pragma unroll
                for (int w = 0; w < 8; ++w) s += awp[w * 512 + tid];
                float gate = sigf((float)a2_s[512 + tid]);
                xh_s[tid] = (f16)(gate * s);
                xh_s[512 + tid] = h_s[tid];
            }
            __syncthreads();

            // ---- stage 5: gates matvec (4 outs/thread, dbuf 8-load groups) + cell ----
            float cn, hn;
            {
                float g0 = 0.f, g1 = 0.f, g2 = 0.f, g3 = 0.f;
                const f16* wbase = Bp + 8 * tid;
                uint4 wA[8], wB[8];
#pragma unroll
                for (int u = 0; u < 8; ++u)
                    wA[u] = *(const uint4*)(wbase + (size_t)u * 4096);
                for (int kko = 0; kko < 64; kko += 2) {
                    const f16* wpB = wbase + (size_t)(kko + 1) * 8 * 4096;
#pragma unroll
                    for (int u = 0; u < 8; ++u)
                        wB[u] = *(const uint4*)(wpB + (size_t)u * 4096);
                    {
                        uint4 xa = *(const uint4*)&xh_s[kko * 16];
                        uint4 xb = *(const uint4*)&xh_s[kko * 16 + 8];
                        unsigned xw[8] = {xa.x, xa.y, xa.z, xa.w, xb.x, xb.y, xb.z, xb.w};
#pragma unroll
                        for (int u = 0; u < 8; ++u) {
                            f16x2 xp = asf16x2(xw[u]);
                            g0 = dotp(asf16x2(wA[u].x), xp, g0);
                            g1 = dotp(asf16x2(wA[u].y), xp, g1);
                            g2 = dotp(asf16x2(wA[u].z), xp, g2);
                            g3 = dotp(asf16x2(wA[u].w), xp, g3);
                        }
                    }
                    if (kko + 2 < 64) {
                        const f16* wpA = wbase + (size_t)(kko + 2) * 8 * 4096;
#pragma unroll
                        for (int u = 0; u < 8; ++u)
                            wA[u] = *(const uint4*)(wpA + (size_t)u * 4096);
                    }
                    {
                        uint4 xa = *(const uint4*)&xh_s[(kko + 1) * 16];
                        uint4 xb = *(const uint4*)&xh_s[(kko + 1) * 16 + 8];
                        unsigned xw[8] = {xa.x, xa.y, xa.z, xa.w, xb.x, xb.y, xb.z, xb.w};
#pragma unroll
                        for (int u = 0; u < 8; ++u) {
                            f16x2 xp = asf16x2(xw[u]);
                            g0 = dotp(asf16x2(wB[u].x), xp, g0);
                            g1 = dotp(asf16x2(wB[u].y), xp, g1);
                            g2 = dotp(asf16x2(wB[u].z), xp, g2);
                            g3 = dotp(asf16x2(wB[u].w), xp, g3);
                        }
                    }
                }
                float4 ei = *(const float4*)&embIH[(size_t)(t * 64 + b) * 2048 + 4 * tid];
                float gi = g0 + ei.x, gf = g1 + ei.y, gg = g2 + ei.z, go = g3 + ei.w;
                cn = sigf(gf) * c_s[tid] + sigf(gi) * tanhf(gg);
                hn = sigf(go) * tanhf(cn);
            }
            __syncthreads();   // readers of old h_s/xh_s/c_s done
            c_s[tid] = cn;
            h_s[tid] = (f16)hn;
            __syncthreads();   // h_s complete
            if (tid < 256)
                ast_u((unsigned*)&hbuf[(size_t)(t + 1) * 32768 + b * 512] + tid,
                      *((unsigned*)h_s + tid));
            post_slot(&sdone[b], t + 1);   // syncthreads + flag
        }
    } else {
        // ==================== preds worker ====================
        const int ntile = bid - 64;
        f16* As = (f16*)smem;                         // [64][520]
        const f16* Bt = Wfc_h + (size_t)ntile * 128 * 512;
        const int rr = lane & 15, kg = (lane >> 4) * 8;
        const int wr = wv >> 2, wc = wv & 3;
        const int r0 = (lane >> 4) * 4, ccl = lane & 15;

        for (int t = 0; t < CT; ++t) {
            wait_slots64(sdone, t + 1);
            const f16* Ag = hbuf + (size_t)(t + 1) * 32768;
            for (int ch = tid; ch < 4096; ch += 512) {
                int row = ch >> 6, kc = (ch & 63) * 8;
                f16x8 v = ald_h8(&Ag[row * 512 + kc]);
                *(f16x8*)&As[row * 520 + kc] = v;
            }
            __syncthreads();

            f32x4 acc[2][2] = {};
#pragma unroll 4
            for (int k0 = 0; k0 < 512; k0 += 32) {
                f16x8 bf[2];
#pragma unroll
                for (int ni = 0; ni < 2; ++ni)
                    bf[ni] = *(const f16x8*)&Bt[(size_t)(wc * 32 + ni * 16 + rr) * 512 + k0 + kg];
#pragma unroll
                for (int mi = 0; mi < 2; ++mi) {
                    f16x8 af = *(const f16x8*)&As[(wr * 32 + mi * 16 + rr) * 520 + k0 + kg];
#pragma unroll
                    for (int ni = 0; ni < 2; ++ni)
                        acc[mi][ni] = __builtin_amdgcn_mfma_f32_16x16x32_f16(af, bf[ni], acc[mi][ni], 0, 0, 0);
                }
            }
#pragma unroll
            for (int mi = 0; mi < 2; ++mi) {
#pragma unroll
                for (int ni = 0; ni < 2; ++ni) {
#pragma unroll
                    for (int r = 0; r < 4; ++r) {
                        int m = wr * 32 + mi * 16 + r0 + r;             // batch
                        int n = ntile * 128 + wc * 32 + ni * 16 + ccl;  // vocab
                        if (n < CV) {
                            float val = ((lens[m] - 1) > t) ? (acc[mi][ni][r] + bfc[n]) : 0.f;
                            __builtin_nontemporal_store(val,
                                &outp[(size_t)m * (CT * CV) + (size_t)t * CV + n]);
                        }
                    }
                }
            }
            __syncthreads();   // done with As before next t overwrites
        }
    }
}

// ---------------------------------------------------------------------------
extern "C" void kernel_launch(void* const* d_in, const int* in_sizes, int n_in,
                              void* d_out, int out_size, void* d_ws, size_t ws_size,
                              hipStream_t stream)
{
    const float* enc  = (const float*)d_in[0];
    const int*   caps = (const int*)d_in[1];
    const int*   lens = (const int*)d_in[2];
    const float* emb  = (const float*)d_in[3];
    const float* W_ea = (const float*)d_in[4];
    const float* b_ea = (const float*)d_in[5];
    const float* W_da = (const float*)d_in[6];
    const float* b_da = (const float*)d_in[7];
    const float* W_fa = (const float*)d_in[8];
    const float* b_fa = (const float*)d_in[9];
    const float* W_fb = (const float*)d_in[10];
    const float* b_fb = (const float*)d_in[11];
    const float* W_ih = (const float*)d_in[12];
    const float* W_hh = (const float*)d_in[13];
    const float* b_ih = (const float*)d_in[14];
    const float* b_hh = (const float*)d_in[15];
    const float* W_fc = (const float*)d_in[16];
    const float* b_fc = (const float*)d_in[17];

    float* out = (float*)d_out;
    float* alph_out = out + (size_t)CB * CT * CV;

    char* p = (char*)d_ws;
    auto carve = [&](size_t bytes) {
        char* r = p;
        p += (bytes + 255) & ~(size_t)255;
        return r;
    };
    f16* enc_h   = (f16*)carve((size_t)12544 * 512 * 2);
    f16* att1_h  = (f16*)carve((size_t)12544 * 512 * 2);
    f16* Wea_h   = (f16*)carve((size_t)512 * 512 * 2);
    f16* WdaT    = (f16*)carve((size_t)256 * 1024 * 2 * 2);   // [kk][1024][2]
    f16* Bp      = (f16*)carve((size_t)512 * 2048 * 2 * 2);   // [kk][2048][2]
    f16* WihE_p  = (f16*)carve((size_t)2048 * 512 * 2);
    f16* Wfc_h   = (f16*)carve((size_t)CVP * 512 * 2);
    f16* embg    = (f16*)carve((size_t)1280 * 512 * 2);
    float* embIH = (float*)carve((size_t)1280 * 2048 * 4);
    float* bcat  = (float*)carve(1024 * 4);
    float* bsum_p= (float*)carve(2048 * 4);
    f16* hbuf    = (f16*)carve((size_t)21 * 64 * 512 * 2);
    float* cinit = (float*)carve((size_t)64 * 512 * 4);
    int* gsync   = (int*)carve(4096);

    hipLaunchKernelGGL(k_mega, dim3(4096), dim3(256), 0, stream,
                       enc, W_ea, W_da, W_fb, W_ih, W_hh, W_fc, emb, caps,
                       b_da, b_fb, b_ih, b_hh,
                       enc_h, Wea_h, WdaT, Bp, WihE_p, Wfc_h, embg, bcat, bsum_p, gsync);

    hipLaunchKernelGGL(k_h0, dim3(64), dim3(256), 0, stream, enc, hbuf, cinit);

    // att1 = enc_h @ W_ea^T + b_ea  (M=12544, N=512) -> f16
    hipLaunchKernelGGL((gemm_k512<EPI_F16B>), dim3(4, 98), dim3(256), 0, stream,
                       enc_h, Wea_h, 512, b_ea, (float*)nullptr, att1_h);
    // embIH = embg @ WihE_p^T + bsum_p  (M=1280, N=2048 permuted c=4d+g) -> f32
    hipLaunchKernelGGL((gemm_k512<EPI_F32B>), dim3(16, 10), dim3(256), 0, stream,
                       embg, WihE_p, 2048, bsum_p, embIH, (f16*)nullptr);

    // fused: 64 per-batch recurrence blocks + 235 overlapped preds blocks
    hipLaunchKernelGGL(k_fused, dim3(64 + NTILES), dim3(512), 0, stream,
                       att1_h, enc_h, WdaT, Bp, embIH, W_fa, b_fa, bcat,
                       lens, cinit, hbuf, alph_out, Wfc_h, b_fc, out, gsync);
}

// Round 10
// 766.699 us; speedup vs baseline: 3.3720x; 3.3712x over previous
//
#include <hip/hip_runtime.h>
#include <hip/hip_bf16.h>

typedef _Float16 f16;
typedef __attribute__((ext_vector_type(8))) _Float16 f16x8;
typedef __attribute__((ext_vector_type(2))) _Float16 f16x2;
typedef __attribute__((ext_vector_type(4))) float f32x4;

constexpr int CB = 64, CP = 196, CH = 512, CV = 30000, CVP = 30080, CT = 20;

__device__ __forceinline__ float sigf(float x) { return 1.f / (1.f + __expf(-x)); }

#if defined(__has_builtin)
#if __has_builtin(__builtin_amdgcn_fdot2)
#define HAVE_FDOT2 1
#endif
#endif

__device__ __forceinline__ f16x2 asf16x2(unsigned u) {
    union { unsigned x; f16x2 h; } c; c.x = u; return c.h;
}
__device__ __forceinline__ float dotp(f16x2 a, f16x2 b, float c) {
#ifdef HAVE_FDOT2
    return __builtin_amdgcn_fdot2(a, b, c, false);
#else
    return fmaf((float)a[0], (float)b[0], fmaf((float)a[1], (float)b[1], c));
#endif
}

// ---- relaxed agent-scope (sc1, L3-coherent) helpers
__device__ __forceinline__ unsigned ald_u(const unsigned* p) {
    return __hip_atomic_load(p, __ATOMIC_RELAXED, __HIP_MEMORY_SCOPE_AGENT);
}
__device__ __forceinline__ void ast_u(unsigned* p, unsigned v) {
    __hip_atomic_store(p, v, __ATOMIC_RELAXED, __HIP_MEMORY_SCOPE_AGENT);
}
__device__ __forceinline__ float ald_f(const float* p) {
    return __hip_atomic_load(p, __ATOMIC_RELAXED, __HIP_MEMORY_SCOPE_AGENT);
}
__device__ __forceinline__ void ast_f(float* p, float v) {
    __hip_atomic_store(p, v, __ATOMIC_RELAXED, __HIP_MEMORY_SCOPE_AGENT);
}

// ---- 4-producer slot sync: each batch has a 4-int slot group on ONE line.
// Producer writes its own slot (no RMW). Consumer lanes poll all 4 in parallel.
__device__ __forceinline__ void wait4(const int* slotbase, int target) {
    if (threadIdx.x < 64) {
        for (;;) {
            int v = __hip_atomic_load(slotbase + (threadIdx.x & 3), __ATOMIC_RELAXED,
                                      __HIP_MEMORY_SCOPE_AGENT);
            if (__all(v >= target)) break;
            __builtin_amdgcn_s_sleep(1);
        }
    }
    __builtin_amdgcn_s_barrier();
    __builtin_amdgcn_sched_barrier(0);
}
// producer: __syncthreads drains vmcnt (sc1 data stores reached L3), then post
__device__ __forceinline__ void post4(int* slot, int val) {
    __syncthreads();
    if (threadIdx.x == 0)
        __hip_atomic_store(slot, val, __ATOMIC_RELAXED, __HIP_MEMORY_SCOPE_AGENT);
}

// ---------------------------------------------------------------------------
// mega convert/transpose/prep kernel (one-time prologue)
//   W1q[q][kk][256][2]: quarter-q att2+gate weights, paired-K. Output o<128 ->
//                       att2 dim 128q+o (W_da); o>=128 -> gate dim (W_fb).
//   BpQ[q][kk][512][2]: quarter-q gate weights, outputs o -> c=512q+o (c=4d+g),
//                       K = [xawe(512); h(512)] (W_ih cols 512.. ; W_hh).
//   WihE_p[c][512]    : c = 4d+g rows of W_ih cols 0..511 for the embIH GEMM.
// ---------------------------------------------------------------------------
__device__ __forceinline__ void cvt8(const float* __restrict__ s, f16* __restrict__ d) {
    float4 a = *(const float4*)s;
    float4 b = *(const float4*)(s + 4);
    f16x8 o;
    o[0] = (f16)a.x; o[1] = (f16)a.y; o[2] = (f16)a.z; o[3] = (f16)a.w;
    o[4] = (f16)b.x; o[5] = (f16)b.y; o[6] = (f16)b.z; o[7] = (f16)b.w;
    *(f16x8*)d = o;
}

__global__ __launch_bounds__(256) void k_mega(
    const float* __restrict__ enc, const float* __restrict__ W_ea,
    const float* __restrict__ W_da, const float* __restrict__ W_fb,
    const float* __restrict__ W_ih, const float* __restrict__ W_hh,
    const float* __restrict__ W_fc, const float* __restrict__ emb,
    const int* __restrict__ caps, const float* __restrict__ b_da,
    const float* __restrict__ b_fb, const float* __restrict__ b_ih,
    const float* __restrict__ b_hh,
    f16* __restrict__ enc_h, f16* __restrict__ Wea_h, f16* __restrict__ W1q,
    f16* __restrict__ BpQ, f16* __restrict__ WihE_p, f16* __restrict__ Wfc_h,
    f16* __restrict__ embg, float* __restrict__ bcat, float* __restrict__ bsum_p,
    int* __restrict__ gsync)
{
    constexpr long long E0 = 802816;            // enc cvt
    constexpr long long E1 = E0 + 32768;        // W_ea
    constexpr long long E2 = E1 + 1920000;      // W_fc
    constexpr long long E3 = E2 + 5120;         // Wfc pad zeros
    constexpr long long E4 = E3 + 81920;        // emb gather
    constexpr long long E5 = E4 + 65536;        // W1q   (4q x 256kk x 64 o-grp)
    constexpr long long E6 = E5 + 262144;       // BpQ   (4q x 512kk x 128 o-grp)
    constexpr long long E7 = E6 + 131072;       // WihE_p (2048c x 64)
    constexpr long long E8 = E7 + 3072;         // biases
    constexpr long long TOT = E8 + 4096;        // gsync zero

    for (long long id = (long long)blockIdx.x * 256 + threadIdx.x; id < TOT;
         id += (long long)gridDim.x * 256) {
        if (id < E0) {
            cvt8(enc + id * 8, enc_h + id * 8);
        } else if (id < E1) {
            long long c = id - E0; cvt8(W_ea + c * 8, Wea_h + c * 8);
        } else if (id < E2) {
            long long c = id - E1; cvt8(W_fc + c * 8, Wfc_h + c * 8);
        } else if (id < E3) {
            long long c = id - E2; f16x8 z = {};
            *(f16x8*)&Wfc_h[15360000 + c * 8] = z;
        } else if (id < E4) {
            long long c = id - E3; int m = (int)(c >> 6), j = (int)(c & 63);
            int tt = m >> 6, bb = m & 63;
            int row = caps[bb * 21 + tt];
            cvt8(emb + (size_t)row * 512 + j * 8, embg + (size_t)m * 512 + j * 8);
        } else if (id < E5) {
            long long c = id - E4;
            int qq = (int)(c >> 14), kk = (int)((c >> 6) & 255);
            int o0 = (int)(c & 63) * 4;
            f16x8 o;
#pragma unroll
            for (int d = 0; d < 4; ++d) {
                int ox = o0 + d;
                const float* src = (ox < 128) ? &W_da[(size_t)(128 * qq + ox) * 512]
                                              : &W_fb[(size_t)(128 * qq + ox - 128) * 512];
                o[2 * d]     = (f16)src[2 * kk];
                o[2 * d + 1] = (f16)src[2 * kk + 1];
            }
            *(f16x8*)&W1q[((size_t)(qq * 256 + kk) * 256 + o0) * 2] = o;
        } else if (id < E6) {
            long long c = id - E5;
            int qq = (int)(c >> 16), kk = (int)((c >> 7) & 511);
            int o0 = (int)(c & 127) * 4;
            f16x8 o;
#pragma unroll
            for (int dd = 0; dd < 4; ++dd) {
                int ox = o0 + dd;
                int d = 128 * qq + (ox >> 2), g = ox & 3;
                int r = g * 512 + d;
#pragma unroll
                for (int j = 0; j < 2; ++j) {
                    int k = 2 * kk + j;
                    float v = (k < 512) ? W_ih[(size_t)r * 1024 + 512 + k]
                                        : W_hh[(size_t)r * 512 + (k - 512)];
                    o[2 * dd + j] = (f16)v;
                }
            }
            *(f16x8*)&BpQ[((size_t)(qq * 512 + kk) * 512 + o0) * 2] = o;
        } else if (id < E7) {
            long long c = id - E6;
            int cc = (int)(c >> 6), j8 = (int)(c & 63);
            int r = (cc & 3) * 512 + (cc >> 2);
            cvt8(W_ih + (size_t)r * 1024 + j8 * 8, WihE_p + (size_t)cc * 512 + j8 * 8);
        } else if (id < E8) {
            int i = (int)(id - E7);
            if (i < 512) bcat[i] = b_da[i];
            else if (i < 1024) bcat[i] = b_fb[i - 512];
            else {
                int cc = i - 1024;
                int r = (cc & 3) * 512 + (cc >> 2);
                bsum_p[cc] = b_ih[r] + b_hh[r];
            }
        } else {
            gsync[(int)(id - E8)] = 0;
        }
    }
}

// h0 = mean_p(enc) -> hbuf slot 0 (f16) and cinit (f32)
__global__ __launch_bounds__(256) void k_h0(const float* __restrict__ enc,
                                            f16* __restrict__ hbuf, float* __restrict__ cinit)
{
    int b = blockIdx.x;
    for (int h = threadIdx.x; h < CH; h += 256) {
        const float* p = enc + (size_t)b * CP * CH + h;
        float s = 0.f;
        for (int q = 0; q < CP; ++q) s += p[q * CH];
        s *= (1.f / 196.f);
        hbuf[b * CH + h] = (f16)s;
        cinit[b * CH + h] = s;
    }
}

// ---------------------------------------------------------------------------
// K=512 GEMM (prologue + preds): tile 128x128, BK=32, padded LDS, reg prefetch
// ---------------------------------------------------------------------------
enum { EPI_F16B = 0, EPI_F32B = 1, EPI_PREDS = 2 };

template <int EPI>
__global__ __launch_bounds__(256) void gemm_k512(
    const f16* __restrict__ Aptr, const f16* __restrict__ Bptr, int N,
    const float* __restrict__ bias, float* __restrict__ Cf,
    f16* __restrict__ Ch, const int* __restrict__ lengths)
{
    constexpr int LD = 40;
    const int tid = threadIdx.x;
    const int lane = tid & 63, wave = tid >> 6;
    const int wr = wave >> 1, wc = wave & 1;
    const int bx = (EPI == EPI_PREDS) ? blockIdx.y : blockIdx.x;
    const int by = (EPI == EPI_PREDS) ? blockIdx.x : blockIdx.y;

    __shared__ f16 As[128 * LD];
    __shared__ f16 Bs[128 * LD];

    const f16* Ag = Aptr + (size_t)by * 128 * 512;
    const f16* Bg = Bptr + (size_t)bx * 128 * 512;

    int srow[2], skc[2];
#pragma unroll
    for (int i = 0; i < 2; ++i) { int ci = tid + i * 256; srow[i] = ci >> 2; skc[i] = (ci & 3) * 8; }

    f32x4 acc[4][4] = {};
    f16x8 ar[2], br[2];
#pragma unroll
    for (int i = 0; i < 2; ++i) {
        ar[i] = *(const f16x8*)&Ag[(size_t)srow[i] * 512 + skc[i]];
        br[i] = *(const f16x8*)&Bg[(size_t)srow[i] * 512 + skc[i]];
    }

    const int rr = lane & 15, kg = (lane >> 4) * 8;
    for (int kt = 0; kt < 16; ++kt) {
        __syncthreads();
#pragma unroll
        for (int i = 0; i < 2; ++i) {
            *(f16x8*)&As[srow[i] * LD + skc[i]] = ar[i];
            *(f16x8*)&Bs[srow[i] * LD + skc[i]] = br[i];
        }
        __syncthreads();
        if (kt < 15) {
            int k0 = (kt + 1) * 32;
#pragma unroll
            for (int i = 0; i < 2; ++i) {
                ar[i] = *(const f16x8*)&Ag[(size_t)srow[i] * 512 + k0 + skc[i]];
                br[i] = *(const f16x8*)&Bg[(size_t)srow[i] * 512 + k0 + skc[i]];
            }
        }
        f16x8 af[4], bf[4];
#pragma unroll
        for (int mi = 0; mi < 4; ++mi) af[mi] = *(const f16x8*)&As[(wr * 64 + mi * 16 + rr) * LD + kg];
#pragma unroll
        for (int ni = 0; ni < 4; ++ni) bf[ni] = *(const f16x8*)&Bs[(wc * 64 + ni * 16 + rr) * LD + kg];
#pragma unroll
        for (int mi = 0; mi < 4; ++mi)
#pragma unroll
            for (int ni = 0; ni < 4; ++ni)
                acc[mi][ni] = __builtin_amdgcn_mfma_f32_16x16x32_f16(af[mi], bf[ni], acc[mi][ni], 0, 0, 0);
    }

    const int m0 = by * 128 + wr * 64;
    const int n0 = bx * 128 + wc * 64;
    const int r0 = (lane >> 4) * 4, cc = lane & 15;
#pragma unroll
    for (int mi = 0; mi < 4; ++mi) {
#pragma unroll
        for (int ni = 0; ni < 4; ++ni) {
#pragma unroll
            for (int r = 0; r < 4; ++r) {
                int m = m0 + mi * 16 + r0 + r;
                int n = n0 + ni * 16 + cc;
                float v = acc[mi][ni][r];
                if constexpr (EPI == EPI_F16B) {
                    Ch[(size_t)m * N + n] = (f16)(v + bias[n]);
                } else if constexpr (EPI == EPI_F32B) {
                    Cf[(size_t)m * N + n] = v + bias[n];
                } else {
                    if (n < CV) {
                        int tt = m >> 6, b = m & 63;
                        float val = ((lengths[b] - 1) > tt) ? (v + bias[n]) : 0.f;
                        __builtin_nontemporal_store(val, &Cf[(size_t)b * (CT * CV) + (size_t)tt * CV + n]);
                    }
                }
            }
        }
    }
}

// ---------------------------------------------------------------------------
// Recurrence: 256 blocks = 64 batches x 4 quarter-blocks, 512 threads.
// Sync domain = the 4 blocks of one batch (slot group on one cache line).
// Block (b,q) owns: att2/gate dims [128q,128q+128), e-rows [49q,49q+49),
// awe h-slice, gate outputs c in [512q,512q+512), c-state slice (LDS).
// 4 tiny slice exchanges per step through L3 (sc1), 4 waits of 4 slots.
// ---------------------------------------------------------------------------
__global__ __launch_bounds__(512) void k_loop4(
    const f16* __restrict__ att1, const f16* __restrict__ ench,
    const f16* __restrict__ W1q, const f16* __restrict__ BpQ,
    const float* __restrict__ embIH, const float* __restrict__ Wfa,
    const float* __restrict__ bfa, const float* __restrict__ bcat,
    const int* __restrict__ lens, const float* __restrict__ cinit,
    f16* __restrict__ hbuf, float* __restrict__ alph,
    float* __restrict__ xatt2, float* __restrict__ xe,
    float* __restrict__ xxa, int* __restrict__ gsync)
{
    const int bid = blockIdx.x, tid = threadIdx.x;
    const int lane = tid & 63, wv = tid >> 6;
    const int b = bid >> 2, q = bid & 3;   // bid = 4b+q -> one q per XCD

    int* s1 = gsync + b * 16;
    int* s2 = gsync + 1024 + b * 16;
    int* s3 = gsync + 2048 + b * 16;
    int* s4 = gsync + 3072 + b * 16;

    __shared__ f16 h_s[512];
    __shared__ float c_s[128];
    __shared__ float a2f[512];
    __shared__ float ga_s[128];
    __shared__ float es[196], als[196], red[16];
    __shared__ float part1[2][256];
    __shared__ float awp[8][128];
    __shared__ f16 xh_s[1024];
    __shared__ float gt[512];
    __shared__ f16 htmp[128];

    if (tid < 256) ((unsigned*)h_s)[tid] = ((const unsigned*)(hbuf + b * 512))[tid];
    if (tid < 128) c_s[tid] = cinit[b * 512 + 128 * q + tid];
    const float bfa0 = bfa[0];
    const int lb = lens[b];
    float wfr[8];
#pragma unroll
    for (int j = 0; j < 8; ++j) wfr[j] = Wfa[lane * 8 + j];
    const int kh = tid >> 8, oo = tid & 255;
    __syncthreads();

    for (int t = 0; t < CT; ++t) {
        if (t > 0) {
            wait4(s4, t);
            if (tid < 256)
                ((unsigned*)h_s)[tid] =
                    ald_u((const unsigned*)(hbuf + (size_t)t * 32768 + b * 512) + tid);
            __syncthreads();
        }

        // ---- phase 1: att2/gate slice matvec (256 outs, K=512, K-split 2) ----
        {
            const f16* wp = W1q + ((size_t)(q * 256 + kh * 128) * 256 + oo) * 2;
            float acc = 0.f;
            for (int k8 = 0; k8 < 16; ++k8) {
                unsigned w[8];
#pragma unroll
                for (int u = 0; u < 8; ++u)
                    w[u] = *(const unsigned*)(wp + (size_t)(k8 * 8 + u) * 512);
#pragma unroll
                for (int u = 0; u < 8; ++u)
                    acc = dotp(asf16x2(w[u]),
                               asf16x2(((unsigned*)h_s)[kh * 128 + k8 * 8 + u]), acc);
            }
            part1[kh][oo] = acc;
        }
        __syncthreads();
        if (tid < 256) {
            float v = part1[0][tid] + part1[1][tid];
            if (tid < 128) {
                v += bcat[128 * q + tid];
                a2f[128 * q + tid] = v;
                ast_f(&xatt2[b * 512 + 128 * q + tid], v);
            } else {
                ga_s[tid - 128] = v + bcat[512 + 128 * q + (tid - 128)];
            }
        }
        post4(s1 + q, t + 1);
        wait4(s1, t + 1);
        a2f[tid] = ald_f(&xatt2[b * 512 + tid]);   // tid<512 covers all (own incl.)
        __syncthreads();

        // ---- phase 2: e rows [49q, 49q+49) ----
        {
            float a2r[8];
#pragma unroll
            for (int j = 0; j < 8; ++j) a2r[j] = a2f[lane * 8 + j];
            for (int p = 49 * q + wv; p < 49 * (q + 1); p += 8) {
                f16x8 av = *(const f16x8*)&att1[((size_t)b * CP + p) * 512 + lane * 8];
                float e = 0.f;
#pragma unroll
                for (int j = 0; j < 8; ++j)
                    e += fmaxf((float)av[j] + a2r[j], 0.f) * wfr[j];
#pragma unroll
                for (int o = 32; o; o >>= 1) e += __shfl_down(e, o);
                if (lane == 0) ast_f(&xe[b * 196 + p], e + bfa0);
            }
        }
        post4(s2 + q, t + 1);
        wait4(s2, t + 1);
        if (tid < CP) es[tid] = ald_f(&xe[b * 196 + tid]);
        __syncthreads();

        // ---- phase 3: softmax (replicated) + awe h-slice + xawe ----
        {
            float ev = (tid < CP) ? es[tid] : -1e30f;
            float mx = ev;
#pragma unroll
            for (int o = 32; o; o >>= 1) mx = fmaxf(mx, __shfl_down(mx, o));
            if (lane == 0) red[wv] = mx;
            __syncthreads();
            mx = red[0];
#pragma unroll
            for (int w = 1; w < 8; ++w) mx = fmaxf(mx, red[w]);
            float ex = (tid < CP) ? __expf(ev - mx) : 0.f;
            float sm = ex;
#pragma unroll
            for (int o = 32; o; o >>= 1) sm += __shfl_down(sm, o);
            if (lane == 0) red[8 + wv] = sm;
            __syncthreads();
            sm = red[8];
#pragma unroll
            for (int w = 1; w < 8; ++w) sm += red[8 + w];
            float al = ex / sm;
            if (tid < CP) {
                als[tid] = al;
                if (tid >= 49 * q && tid < 49 * (q + 1))
                    alph[(size_t)b * (CT * CP) + t * CP + tid] = ((lb - 1) > t) ? al : 0.f;
            }
        }
        __syncthreads();
        {
            float aw0 = 0.f, aw1 = 0.f;
            for (int p = wv; p < CP; p += 8) {
                float a = als[p];
                f16x2 e2 = *(const f16x2*)&ench[((size_t)b * CP + p) * 512 + 128 * q + lane * 2];
                aw0 = fmaf(a, (float)e2[0], aw0);
                aw1 = fmaf(a, (float)e2[1], aw1);
            }
            awp[wv][lane * 2] = aw0;
            awp[wv][lane * 2 + 1] = aw1;
        }
        __syncthreads();
        if (tid < 128) {
            float s = 0.f;
#pragma unroll
            for (int w = 0; w < 8; ++w) s += awp[w][tid];
            ast_f(&xxa[b * 512 + 128 * q + tid], sigf(ga_s[tid]) * s);
        }
        post4(s3 + q, t + 1);
        wait4(s3, t + 1);
        xh_s[tid] = (f16)ald_f(&xxa[b * 512 + tid]);
        xh_s[512 + tid] = h_s[tid];
        __syncthreads();

        // ---- phase 4: gates slice (512 outs, K=1024) + cell + h post ----
        {
            const f16* wp = BpQ + ((size_t)q * 512 * 512 + tid) * 2;
            float g = 0.f;
            for (int k8 = 0; k8 < 64; ++k8) {
                unsigned w[8];
#pragma unroll
                for (int u = 0; u < 8; ++u)
                    w[u] = *(const unsigned*)(wp + (size_t)(k8 * 8 + u) * 1024);
#pragma unroll
                for (int u = 0; u < 8; ++u)
                    g = dotp(asf16x2(w[u]), asf16x2(((unsigned*)xh_s)[k8 * 8 + u]), g);
            }
            gt[tid] = g + embIH[(size_t)(t * 64 + b) * 2048 + 512 * q + tid];
        }
        __syncthreads();
        if (tid < 128) {
            float gi = gt[4 * tid], gf = gt[4 * tid + 1];
            float gg = gt[4 * tid + 2], go = gt[4 * tid + 3];
            float cn = sigf(gf) * c_s[tid] + sigf(gi) * tanhf(gg);
            c_s[tid] = cn;
            htmp[tid] = (f16)(sigf(go) * tanhf(cn));
        }
        __syncthreads();
        if (tid < 64) {
            union { f16 h[2]; unsigned u; } pk;
            pk.h[0] = htmp[2 * tid]; pk.h[1] = htmp[2 * tid + 1];
            ast_u((unsigned*)&hbuf[(size_t)(t + 1) * 32768 + b * 512 + 128 * q] + tid, pk.u);
        }
        post4(s4 + q, t + 1);
    }
}

// ---------------------------------------------------------------------------
extern "C" void kernel_launch(void* const* d_in, const int* in_sizes, int n_in,
                              void* d_out, int out_size, void* d_ws, size_t ws_size,
                              hipStream_t stream)
{
    const float* enc  = (const float*)d_in[0];
    const int*   caps = (const int*)d_in[1];
    const int*   lens = (const int*)d_in[2];
    const float* emb  = (const float*)d_in[3];
    const float* W_ea = (const float*)d_in[4];
    const float* b_ea = (const float*)d_in[5];
    const float* W_da = (const float*)d_in[6];
    const float* b_da = (const float*)d_in[7];
    const float* W_fa = (const float*)d_in[8];
    const float* b_fa = (const float*)d_in[9];
    const float* W_fb = (const float*)d_in[10];
    const float* b_fb = (const float*)d_in[11];
    const float* W_ih = (const float*)d_in[12];
    const float* W_hh = (const float*)d_in[13];
    const float* b_ih = (const float*)d_in[14];
    const float* b_hh = (const float*)d_in[15];
    const float* W_fc = (const float*)d_in[16];
    const float* b_fc = (const float*)d_in[17];

    float* out = (float*)d_out;
    float* alph_out = out + (size_t)CB * CT * CV;

    char* p = (char*)d_ws;
    auto carve = [&](size_t bytes) {
        char* r = p;
        p += (bytes + 255) & ~(size_t)255;
        return r;
    };
    f16* enc_h   = (f16*)carve((size_t)12544 * 512 * 2);
    f16* att1_h  = (f16*)carve((size_t)12544 * 512 * 2);
    f16* Wea_h   = (f16*)carve((size_t)512 * 512 * 2);
    f16* W1q     = (f16*)carve((size_t)4 * 256 * 256 * 2 * 2);  // [q][kk][256][2]
    f16* BpQ     = (f16*)carve((size_t)4 * 512 * 512 * 2 * 2);  // [q][kk][512][2]
    f16* WihE_p  = (f16*)carve((size_t)2048 * 512 * 2);
    f16* Wfc_h   = (f16*)carve((size_t)CVP * 512 * 2);
    f16* embg    = (f16*)carve((size_t)1280 * 512 * 2);
    float* embIH = (float*)carve((size_t)1280 * 2048 * 4);
    float* bcat  = (float*)carve(1024 * 4);
    float* bsum_p= (float*)carve(2048 * 4);
    f16* hbuf    = (f16*)carve((size_t)21 * 64 * 512 * 2);
    float* cinit = (float*)carve((size_t)64 * 512 * 4);
    float* xatt2 = (float*)carve((size_t)64 * 512 * 4);
    float* xe    = (float*)carve((size_t)64 * 196 * 4);
    float* xxa   = (float*)carve((size_t)64 * 512 * 4);
    int* gsync   = (int*)carve(4096 * 4);

    hipLaunchKernelGGL(k_mega, dim3(4096), dim3(256), 0, stream,
                       enc, W_ea, W_da, W_fb, W_ih, W_hh, W_fc, emb, caps,
                       b_da, b_fb, b_ih, b_hh,
                       enc_h, Wea_h, W1q, BpQ, WihE_p, Wfc_h, embg, bcat, bsum_p, gsync);

    hipLaunchKernelGGL(k_h0, dim3(64), dim3(256), 0, stream, enc, hbuf, cinit);

    // att1 = enc_h @ W_ea^T + b_ea  (M=12544, N=512) -> f16
    hipLaunchKernelGGL((gemm_k512<EPI_F16B>), dim3(4, 98), dim3(256), 0, stream,
                       enc_h, Wea_h, 512, b_ea, (float*)nullptr, att1_h, (const int*)nullptr);
    // embIH = embg @ WihE_p^T + bsum_p  (M=1280, N=2048 permuted c=4d+g) -> f32
    hipLaunchKernelGGL((gemm_k512<EPI_F32B>), dim3(16, 10), dim3(256), 0, stream,
                       embg, WihE_p, 2048, bsum_p, embIH, (f16*)nullptr, (const int*)nullptr);

    // 20-step recurrence: 64 batches x 4 quarter-blocks, 4-block slot sync
    hipLaunchKernelGGL(k_loop4, dim3(256), dim3(512), 0, stream,
                       att1_h, enc_h, W1q, BpQ, embIH, W_fa, b_fa, bcat,
                       lens, cinit, hbuf, alph_out, xatt2, xe, xxa, gsync);

    // predictions = h(1..20) @ W_fc^T + b_fc, masked scatter
    hipLaunchKernelGGL((gemm_k512<EPI_PREDS>), dim3(10, CVP / 128), dim3(256), 0, stream,
                       hbuf + 32768, Wfc_h, CVP, b_fc, out, (f16*)nullptr, lens);
}

// Round 11
// 553.848 us; speedup vs baseline: 4.6679x; 1.3843x over previous
//
#include <hip/hip_runtime.h>
#include <hip/hip_bf16.h>

typedef _Float16 f16;
typedef __attribute__((ext_vector_type(8))) _Float16 f16x8;
typedef __attribute__((ext_vector_type(2))) _Float16 f16x2;
typedef __attribute__((ext_vector_type(4))) float f32x4;

constexpr int CB = 64, CP = 196, CH = 512, CV = 30000, CVP = 30080, CT = 20;
constexpr int NT = 235;  // preds col tiles

__device__ __forceinline__ float sigf(float x) { return 1.f / (1.f + __expf(-x)); }

#if defined(__has_builtin)
#if __has_builtin(__builtin_amdgcn_fdot2)
#define HAVE_FDOT2 1
#endif
#endif

__device__ __forceinline__ f16x2 asf16x2(unsigned u) {
    union { unsigned x; f16x2 h; } c; c.x = u; return c.h;
}
__device__ __forceinline__ float dotp(f16x2 a, f16x2 b, float c) {
#ifdef HAVE_FDOT2
    return __builtin_amdgcn_fdot2(a, b, c, false);
#else
    return fmaf((float)a[0], (float)b[0], fmaf((float)a[1], (float)b[1], c));
#endif
}

// ---- relaxed agent-scope (sc1, L3-coherent) helpers
__device__ __forceinline__ unsigned ald_u(const unsigned* p) {
    return __hip_atomic_load(p, __ATOMIC_RELAXED, __HIP_MEMORY_SCOPE_AGENT);
}
__device__ __forceinline__ void ast_u(unsigned* p, unsigned v) {
    __hip_atomic_store(p, v, __ATOMIC_RELAXED, __HIP_MEMORY_SCOPE_AGENT);
}
__device__ __forceinline__ float ald_f(const float* p) {
    return __hip_atomic_load(p, __ATOMIC_RELAXED, __HIP_MEMORY_SCOPE_AGENT);
}
__device__ __forceinline__ void ast_f(float* p, float v) {
    __hip_atomic_store(p, v, __ATOMIC_RELAXED, __HIP_MEMORY_SCOPE_AGENT);
}

// ---- 4-producer slot sync (one cache line per batch); producer writes own
// slot (no RMW); consumer lanes poll all 4 in parallel; raw s_barrier release.
__device__ __forceinline__ void wait4(const int* slotbase, int target) {
    if (threadIdx.x < 64) {
        for (;;) {
            int v = __hip_atomic_load(slotbase + (threadIdx.x & 3), __ATOMIC_RELAXED,
                                      __HIP_MEMORY_SCOPE_AGENT);
            if (__all(v >= target)) break;
            __builtin_amdgcn_s_sleep(1);
        }
    }
    __builtin_amdgcn_s_barrier();
    __builtin_amdgcn_sched_barrier(0);
}
__device__ __forceinline__ void post4(int* slot, int val) {
    __syncthreads();
    if (threadIdx.x == 0)
        __hip_atomic_store(slot, val, __ATOMIC_RELAXED, __HIP_MEMORY_SCOPE_AGENT);
}

// ---------------------------------------------------------------------------
// mega convert/transpose/prep kernel (one-time prologue)
//   W1q4[q][kk4(64)][o(256)][8] : o<128 -> att2 dim 128q+o (W_da row, k chunk
//                                 8*kk4..8*kk4+7); o>=128 -> gate dim (W_fb)
//   BpQ4[q][kk4(128)][o(512)][8]: out c=512q+o (c=4d+g), K=[xawe;h] chunk 8*kk4
//   WihE_p[c][512]              : c = 4d+g rows of W_ih cols 0..511
// ---------------------------------------------------------------------------
__device__ __forceinline__ void cvt8(const float* __restrict__ s, f16* __restrict__ d) {
    float4 a = *(const float4*)s;
    float4 b = *(const float4*)(s + 4);
    f16x8 o;
    o[0] = (f16)a.x; o[1] = (f16)a.y; o[2] = (f16)a.z; o[3] = (f16)a.w;
    o[4] = (f16)b.x; o[5] = (f16)b.y; o[6] = (f16)b.z; o[7] = (f16)b.w;
    *(f16x8*)d = o;
}

__global__ __launch_bounds__(256) void k_mega(
    const float* __restrict__ enc, const float* __restrict__ W_ea,
    const float* __restrict__ W_da, const float* __restrict__ W_fb,
    const float* __restrict__ W_ih, const float* __restrict__ W_hh,
    const float* __restrict__ W_fc, const float* __restrict__ emb,
    const int* __restrict__ caps, const float* __restrict__ b_da,
    const float* __restrict__ b_fb, const float* __restrict__ b_ih,
    const float* __restrict__ b_hh,
    f16* __restrict__ enc_h, f16* __restrict__ Wea_h, f16* __restrict__ W1q4,
    f16* __restrict__ BpQ4, f16* __restrict__ WihE_p, f16* __restrict__ Wfc_h,
    f16* __restrict__ embg, float* __restrict__ bcat, float* __restrict__ bsum_p,
    int* __restrict__ gsync)
{
    constexpr long long E0 = 802816;            // enc cvt
    constexpr long long E1 = E0 + 32768;        // W_ea
    constexpr long long E2 = E1 + 1920000;      // W_fc
    constexpr long long E3 = E2 + 5120;         // Wfc pad zeros
    constexpr long long E4 = E3 + 81920;        // emb gather
    constexpr long long E5 = E4 + 65536;        // W1q4  (4q x 64kk4 x 256o)
    constexpr long long E6 = E5 + 262144;       // BpQ4  (4q x 128kk4 x 512o)
    constexpr long long E7 = E6 + 131072;       // WihE_p (2048c x 64)
    constexpr long long E8 = E7 + 3072;         // biases
    constexpr long long TOT = E8 + 4096;        // gsync zero

    for (long long id = (long long)blockIdx.x * 256 + threadIdx.x; id < TOT;
         id += (long long)gridDim.x * 256) {
        if (id < E0) {
            cvt8(enc + id * 8, enc_h + id * 8);
        } else if (id < E1) {
            long long c = id - E0; cvt8(W_ea + c * 8, Wea_h + c * 8);
        } else if (id < E2) {
            long long c = id - E1; cvt8(W_fc + c * 8, Wfc_h + c * 8);
        } else if (id < E3) {
            long long c = id - E2; f16x8 z = {};
            *(f16x8*)&Wfc_h[15360000 + c * 8] = z;
        } else if (id < E4) {
            long long c = id - E3; int m = (int)(c >> 6), j = (int)(c & 63);
            int tt = m >> 6, bb = m & 63;
            int row = caps[bb * 21 + tt];
            cvt8(emb + (size_t)row * 512 + j * 8, embg + (size_t)m * 512 + j * 8);
        } else if (id < E5) {
            long long c = id - E4;
            int qq = (int)(c >> 14), kk4 = (int)((c >> 8) & 63), o = (int)(c & 255);
            const float* src = (o < 128) ? &W_da[(size_t)(128 * qq + o) * 512]
                                         : &W_fb[(size_t)(128 * qq + o - 128) * 512];
            cvt8(src + kk4 * 8, &W1q4[(((size_t)qq * 64 + kk4) * 256 + o) * 8]);
        } else if (id < E6) {
            long long c = id - E5;
            int qq = (int)(c >> 16), kk4 = (int)((c >> 9) & 127), o = (int)(c & 511);
            int d = 128 * qq + (o >> 2), g = o & 3;
            int r = g * 512 + d;
            const float* src = (kk4 < 64) ? &W_ih[(size_t)r * 1024 + 512 + kk4 * 8]
                                          : &W_hh[(size_t)r * 512 + kk4 * 8 - 512];
            cvt8(src, &BpQ4[(((size_t)qq * 128 + kk4) * 512 + o) * 8]);
        } else if (id < E7) {
            long long c = id - E6;
            int cc = (int)(c >> 6), j8 = (int)(c & 63);
            int r = (cc & 3) * 512 + (cc >> 2);
            cvt8(W_ih + (size_t)r * 1024 + j8 * 8, WihE_p + (size_t)cc * 512 + j8 * 8);
        } else if (id < E8) {
            int i = (int)(id - E7);
            if (i < 512) bcat[i] = b_da[i];
            else if (i < 1024) bcat[i] = b_fb[i - 512];
            else {
                int cc = i - 1024;
                int r = (cc & 3) * 512 + (cc >> 2);
                bsum_p[cc] = b_ih[r] + b_hh[r];
            }
        } else {
            gsync[(int)(id - E8)] = 0;
        }
    }
}

// h0 = mean_p(enc) -> hbuf slot 0 (f16) and cinit (f32)
__global__ __launch_bounds__(256) void k_h0(const float* __restrict__ enc,
                                            f16* __restrict__ hbuf, float* __restrict__ cinit)
{
    int b = blockIdx.x;
    for (int h = threadIdx.x; h < CH; h += 256) {
        const float* p = enc + (size_t)b * CP * CH + h;
        float s = 0.f;
        for (int q = 0; q < CP; ++q) s += p[q * CH];
        s *= (1.f / 196.f);
        hbuf[b * CH + h] = (f16)s;
        cinit[b * CH + h] = s;
    }
}

// ---------------------------------------------------------------------------
// K=512 GEMM: tile 128x128, BK=32, padded LDS, reg prefetch.
// EPI_PREDS uses a 1-D grid of 2400 with an XCD-pinning swizzle: all 10
// m-tiles of a W_fc column tile share bid%8 -> same XCD L2 (B fetched once).
// ---------------------------------------------------------------------------
enum { EPI_F16B = 0, EPI_F32B = 1, EPI_PREDS = 2 };

template <int EPI>
__global__ __launch_bounds__(256) void gemm_k512(
    const f16* __restrict__ Aptr, const f16* __restrict__ Bptr, int N,
    const float* __restrict__ bias, float* __restrict__ Cf,
    f16* __restrict__ Ch, const int* __restrict__ lengths)
{
    constexpr int LD = 40;
    const int tid = threadIdx.x;
    const int lane = tid & 63, wave = tid >> 6;
    const int wr = wave >> 1, wc = wave & 1;
    int bx, by;
    if constexpr (EPI == EPI_PREDS) {
        int bid1 = blockIdx.x;
        int nt = (bid1 / 80) * 8 + (bid1 & 7);
        int mt = (bid1 >> 3) % 10;
        if (nt >= NT) return;
        bx = nt; by = mt;
    } else {
        bx = blockIdx.x; by = blockIdx.y;
    }

    __shared__ f16 As[128 * LD];
    __shared__ f16 Bs[128 * LD];

    const f16* Ag = Aptr + (size_t)by * 128 * 512;
    const f16* Bg = Bptr + (size_t)bx * 128 * 512;

    int srow[2], skc[2];
#pragma unroll
    for (int i = 0; i < 2; ++i) { int ci = tid + i * 256; srow[i] = ci >> 2; skc[i] = (ci & 3) * 8; }

    f32x4 acc[4][4] = {};
    f16x8 ar[2], br[2];
#pragma unroll
    for (int i = 0; i < 2; ++i) {
        ar[i] = *(const f16x8*)&Ag[(size_t)srow[i] * 512 + skc[i]];
        br[i] = *(const f16x8*)&Bg[(size_t)srow[i] * 512 + skc[i]];
    }

    const int rr = lane & 15, kg = (lane >> 4) * 8;
    for (int kt = 0; kt < 16; ++kt) {
        __syncthreads();
#pragma unroll
        for (int i = 0; i < 2; ++i) {
            *(f16x8*)&As[srow[i] * LD + skc[i]] = ar[i];
            *(f16x8*)&Bs[srow[i] * LD + skc[i]] = br[i];
        }
        __syncthreads();
        if (kt < 15) {
            int k0 = (kt + 1) * 32;
#pragma unroll
            for (int i = 0; i < 2; ++i) {
                ar[i] = *(const f16x8*)&Ag[(size_t)srow[i] * 512 + k0 + skc[i]];
                br[i] = *(const f16x8*)&Bg[(size_t)srow[i] * 512 + k0 + skc[i]];
            }
        }
        f16x8 af[4], bf[4];
#pragma unroll
        for (int mi = 0; mi < 4; ++mi) af[mi] = *(const f16x8*)&As[(wr * 64 + mi * 16 + rr) * LD + kg];
#pragma unroll
        for (int ni = 0; ni < 4; ++ni) bf[ni] = *(const f16x8*)&Bs[(wc * 64 + ni * 16 + rr) * LD + kg];
#pragma unroll
        for (int mi = 0; mi < 4; ++mi)
#pragma unroll
            for (int ni = 0; ni < 4; ++ni)
                acc[mi][ni] = __builtin_amdgcn_mfma_f32_16x16x32_f16(af[mi], bf[ni], acc[mi][ni], 0, 0, 0);
    }

    const int m0 = by * 128 + wr * 64;
    const int n0 = bx * 128 + wc * 64;
    const int r0 = (lane >> 4) * 4, cc = lane & 15;
#pragma unroll
    for (int mi = 0; mi < 4; ++mi) {
#pragma unroll
        for (int ni = 0; ni < 4; ++ni) {
#pragma unroll
            for (int r = 0; r < 4; ++r) {
                int m = m0 + mi * 16 + r0 + r;
                int n = n0 + ni * 16 + cc;
                float v = acc[mi][ni][r];
                if constexpr (EPI == EPI_F16B) {
                    Ch[(size_t)m * N + n] = (f16)(v + bias[n]);
                } else if constexpr (EPI == EPI_F32B) {
                    Cf[(size_t)m * N + n] = v + bias[n];
                } else {
                    if (n < CV) {
                        int tt = m >> 6, b = m & 63;
                        float val = ((lengths[b] - 1) > tt) ? (v + bias[n]) : 0.f;
                        __builtin_nontemporal_store(val, &Cf[(size_t)b * (CT * CV) + (size_t)tt * CV + n]);
                    }
                }
            }
        }
    }
}

// ---------------------------------------------------------------------------
// Recurrence: 256 blocks = 64 batches x 4 quarter-blocks, 512 threads.
// r10 structure + 16B/lane weight layouts, 4-acc dot chains, wide awe loads,
// att1/enc prefetch overlapped with the slot syncs.
// ---------------------------------------------------------------------------
__global__ __launch_bounds__(512) void k_loop4(
    const f16* __restrict__ att1, const f16* __restrict__ ench,
    const f16* __restrict__ W1q4, const f16* __restrict__ BpQ4,
    const float* __restrict__ embIH, const float* __restrict__ Wfa,
    const float* __restrict__ bfa, const float* __restrict__ bcat,
    const int* __restrict__ lens, const float* __restrict__ cinit,
    f16* __restrict__ hbuf, float* __restrict__ alph,
    float* __restrict__ xatt2, float* __restrict__ xe,
    float* __restrict__ xxa, int* __restrict__ gsync)
{
    const int bid = blockIdx.x, tid = threadIdx.x;
    const int lane = tid & 63, wv = tid >> 6;
    const int b = bid >> 2, q = bid & 3;   // bid = 4b+q -> one q per XCD pair

    int* s1 = gsync + b * 16;
    int* s2 = gsync + 1024 + b * 16;
    int* s3 = gsync + 2048 + b * 16;
    int* s4 = gsync + 3072 + b * 16;

    __shared__ __align__(16) f16 h_s[512];
    __shared__ float c_s[128];
    __shared__ float a2f[512];
    __shared__ float ga_s[128];
    __shared__ float es[196], als[196], red[16];
    __shared__ float part1[2][256];
    __shared__ float awp[32][128];
    __shared__ __align__(16) f16 xh_s[1024];
    __shared__ float gt[512];
    __shared__ f16 htmp[128];

    if (tid < 256) ((unsigned*)h_s)[tid] = ((const unsigned*)(hbuf + b * 512))[tid];
    if (tid < 128) c_s[tid] = cinit[b * 512 + 128 * q + tid];
    const float bfa0 = bfa[0];
    const int lb = lens[b];
    float wfr[8];
#pragma unroll
    for (int j = 0; j < 8; ++j) wfr[j] = Wfa[lane * 8 + j];
    const int ecnt = (56 - wv) >> 3;          // e rows this wave (7 or 6)
    const int ar_ = lane >> 4, ac_ = lane & 15;  // awe lane mapping
    __syncthreads();

    for (int t = 0; t < CT; ++t) {
        if (t > 0) {
            wait4(s4, t);
            if (tid < 256)
                ((unsigned*)h_s)[tid] =
                    ald_u((const unsigned*)(hbuf + (size_t)t * 32768 + b * 512) + tid);
            __syncthreads();
        }

        // ---- phase 1: att2/gate slice matvec (256 outs, K-split 2, 16B loads) ----
        {
            const int kh = tid >> 8, oo = tid & 255;
            const f16* wp = W1q4 + (((size_t)q * 64 + kh * 32) * 256 + oo) * 8;
            const uint4* xq = (const uint4*)h_s + kh * 32;
            float a0 = 0.f, a1 = 0.f, a2 = 0.f, a3 = 0.f;
#pragma unroll 8
            for (int i = 0; i < 32; ++i) {
                uint4 w = *(const uint4*)(wp + (size_t)i * 2048);
                uint4 xv = xq[i];
                a0 = dotp(asf16x2(w.x), asf16x2(xv.x), a0);
                a1 = dotp(asf16x2(w.y), asf16x2(xv.y), a1);
                a2 = dotp(asf16x2(w.z), asf16x2(xv.z), a2);
                a3 = dotp(asf16x2(w.w), asf16x2(xv.w), a3);
            }
            part1[kh][oo] = (a0 + a1) + (a2 + a3);
        }
        __syncthreads();
        if (tid < 256) {
            float v = part1[0][tid] + part1[1][tid];
            if (tid < 128) {
                v += bcat[128 * q + tid];
                ast_f(&xatt2[b * 512 + 128 * q + tid], v);
            } else {
                ga_s[tid - 128] = v + bcat[512 + 128 * q + (tid - 128)];
            }
        }

        // prefetch att1 e-row fragments (flag-independent; overlaps s1 sync)
        f16x8 fr[7];
#pragma unroll
        for (int i = 0; i < 7; ++i)
            if (i < ecnt)
                fr[i] = *(const f16x8*)&att1[((size_t)b * CP + 49 * q + wv + 8 * i) * 512 + lane * 8];

        post4(s1 + q, t + 1);
        wait4(s1, t + 1);
        a2f[tid] = ald_f(&xatt2[b * 512 + tid]);
        __syncthreads();

        // ---- phase 2: e rows [49q, 49q+49) ----
        {
            float a2r[8];
#pragma unroll
            for (int j = 0; j < 8; ++j) a2r[j] = a2f[lane * 8 + j];
#pragma unroll
            for (int i = 0; i < 7; ++i)
                if (i < ecnt) {
                    float e = 0.f;
#pragma unroll
                    for (int j = 0; j < 8; ++j)
                        e += fmaxf((float)fr[i][j] + a2r[j], 0.f) * wfr[j];
#pragma unroll
                    for (int o = 32; o; o >>= 1) e += __shfl_down(e, o);
                    if (lane == 0) ast_f(&xe[b * 196 + 49 * q + wv + 8 * i], e + bfa0);
                }
        }

        // prefetch enc awe fragments (flag-independent; overlaps s2 sync)
        f16x8 er[7];
#pragma unroll
        for (int it = 0; it < 7; ++it) {
            int p = it * 32 + wv * 4 + ar_;
            if (p < CP)
                er[it] = *(const f16x8*)&ench[((size_t)b * CP + p) * 512 + 128 * q + ac_ * 8];
        }

        post4(s2 + q, t + 1);
        wait4(s2, t + 1);
        if (tid < CP) es[tid] = ald_f(&xe[b * 196 + tid]);
        __syncthreads();

        // ---- phase 3: softmax (replicated) + awe h-slice + xawe ----
        {
            float ev = (tid < CP) ? es[tid] : -1e30f;
            float mx = ev;
#pragma unroll
            for (int o = 32; o; o >>= 1) mx = fmaxf(mx, __shfl_down(mx, o));
            if (lane == 0) red[wv] = mx;
            __syncthreads();
            mx = red[0];
#pragma unroll
            for (int w = 1; w < 8; ++w) mx = fmaxf(mx, red[w]);
            float ex = (tid < CP) ? __expf(ev - mx) : 0.f;
            float sm = ex;
#pragma unroll
            for (int o = 32; o; o >>= 1) sm += __shfl_down(sm, o);
            if (lane == 0) red[8 + wv] = sm;
            __syncthreads();
            sm = red[8];
#pragma unroll
            for (int w = 1; w < 8; ++w) sm += red[8 + w];
            float al = ex / sm;
            if (tid < CP) {
                als[tid] = al;
                if (tid >= 49 * q && tid < 49 * (q + 1))
                    alph[(size_t)b * (CT * CP) + t * CP + tid] = ((lb - 1) > t) ? al : 0.f;
            }
        }
        __syncthreads();
        {
            float aw[8] = {};
#pragma unroll
            for (int it = 0; it < 7; ++it) {
                int p = it * 32 + wv * 4 + ar_;
                if (p < CP) {
                    float a = als[p];
#pragma unroll
                    for (int j = 0; j < 8; ++j) aw[j] = fmaf(a, (float)er[it][j], aw[j]);
                }
            }
#pragma unroll
            for (int j = 0; j < 8; ++j) awp[wv * 4 + ar_][ac_ * 8 + j] = aw[j];
        }
        __syncthreads();
        if (tid < 128) {
            float s = 0.f;
#pragma unroll
            for (int g = 0; g < 32; ++g) s += awp[g][tid];
            ast_f(&xxa[b * 512 + 128 * q + tid], sigf(ga_s[tid]) * s);
        }
        post4(s3 + q, t + 1);
        wait4(s3, t + 1);
        xh_s[tid] = (f16)ald_f(&xxa[b * 512 + tid]);
        xh_s[512 + tid] = h_s[tid];
        __syncthreads();

        // ---- phase 4: gates slice (512 outs, K=1024, 16B loads) + cell ----
        {
            const f16* wp = BpQ4 + ((size_t)q * 128 * 512 + tid) * 8;
            const uint4* xq = (const uint4*)xh_s;
            float a0 = 0.f, a1 = 0.f, a2 = 0.f, a3 = 0.f;
#pragma unroll 8
            for (int i = 0; i < 128; ++i) {
                uint4 w = *(const uint4*)(wp + (size_t)i * 4096);
                uint4 xv = xq[i];
                a0 = dotp(asf16x2(w.x), asf16x2(xv.x), a0);
                a1 = dotp(asf16x2(w.y), asf16x2(xv.y), a1);
                a2 = dotp(asf16x2(w.z), asf16x2(xv.z), a2);
                a3 = dotp(asf16x2(w.w), asf16x2(xv.w), a3);
            }
            gt[tid] = (a0 + a1) + (a2 + a3)
                      + embIH[(size_t)(t * 64 + b) * 2048 + 512 * q + tid];
        }
        __syncthreads();
        if (tid < 128) {
            float gi = gt[4 * tid], gf = gt[4 * tid + 1];
            float gg = gt[4 * tid + 2], go = gt[4 * tid + 3];
            float cn = sigf(gf) * c_s[tid] + sigf(gi) * tanhf(gg);
            c_s[tid] = cn;
            htmp[tid] = (f16)(sigf(go) * tanhf(cn));
        }
        __syncthreads();
        if (tid < 64) {
            union { f16 h[2]; unsigned u; } pk;
            pk.h[0] = htmp[2 * tid]; pk.h[1] = htmp[2 * tid + 1];
            ast_u((unsigned*)&hbuf[(size_t)(t + 1) * 32768 + b * 512 + 128 * q] + tid, pk.u);
        }
        post4(s4 + q, t + 1);
    }
}

// ---------------------------------------------------------------------------
extern "C" void kernel_launch(void* const* d_in, const int* in_sizes, int n_in,
                              void* d_out, int out_size, void* d_ws, size_t ws_size,
                              hipStream_t stream)
{
    const float* enc  = (const float*)d_in[0];
    const int*   caps = (const int*)d_in[1];
    const int*   lens = (const int*)d_in[2];
    const float* emb  = (const float*)d_in[3];
    const float* W_ea = (const float*)d_in[4];
    const float* b_ea = (const float*)d_in[5];
    const float* W_da = (const float*)d_in[6];
    const float* b_da = (const float*)d_in[7];
    const float* W_fa = (const float*)d_in[8];
    const float* b_fa = (const float*)d_in[9];
    const float* W_fb = (const float*)d_in[10];
    const float* b_fb = (const float*)d_in[11];
    const float* W_ih = (const float*)d_in[12];
    const float* W_hh = (const float*)d_in[13];
    const float* b_ih = (const float*)d_in[14];
    const float* b_hh = (const float*)d_in[15];
    const float* W_fc = (const float*)d_in[16];
    const float* b_fc = (const float*)d_in[17];

    float* out = (float*)d_out;
    float* alph_out = out + (size_t)CB * CT * CV;

    char* p = (char*)d_ws;
    auto carve = [&](size_t bytes) {
        char* r = p;
        p += (bytes + 255) & ~(size_t)255;
        return r;
    };
    f16* enc_h   = (f16*)carve((size_t)12544 * 512 * 2);
    f16* att1_h  = (f16*)carve((size_t)12544 * 512 * 2);
    f16* Wea_h   = (f16*)carve((size_t)512 * 512 * 2);
    f16* W1q4    = (f16*)carve((size_t)4 * 64 * 256 * 8 * 2);    // [q][kk4][256][8]
    f16* BpQ4    = (f16*)carve((size_t)4 * 128 * 512 * 8 * 2);   // [q][kk4][512][8]
    f16* WihE_p  = (f16*)carve((size_t)2048 * 512 * 2);
    f16* Wfc_h   = (f16*)carve((size_t)CVP * 512 * 2);
    f16* embg    = (f16*)carve((size_t)1280 * 512 * 2);
    float* embIH = (float*)carve((size_t)1280 * 2048 * 4);
    float* bcat  = (float*)carve(1024 * 4);
    float* bsum_p= (float*)carve(2048 * 4);
    f16* hbuf    = (f16*)carve((size_t)21 * 64 * 512 * 2);
    float* cinit = (float*)carve((size_t)64 * 512 * 4);
    float* xatt2 = (float*)carve((size_t)64 * 512 * 4);
    float* xe    = (float*)carve((size_t)64 * 196 * 4);
    float* xxa   = (float*)carve((size_t)64 * 512 * 4);
    int* gsync   = (int*)carve(4096 * 4);

    hipLaunchKernelGGL(k_mega, dim3(4096), dim3(256), 0, stream,
                       enc, W_ea, W_da, W_fb, W_ih, W_hh, W_fc, emb, caps,
                       b_da, b_fb, b_ih, b_hh,
                       enc_h, Wea_h, W1q4, BpQ4, WihE_p, Wfc_h, embg, bcat, bsum_p, gsync);

    hipLaunchKernelGGL(k_h0, dim3(64), dim3(256), 0, stream, enc, hbuf, cinit);

    // att1 = enc_h @ W_ea^T + b_ea  (M=12544, N=512) -> f16
    hipLaunchKernelGGL((gemm_k512<EPI_F16B>), dim3(4, 98), dim3(256), 0, stream,
                       enc_h, Wea_h, 512, b_ea, (float*)nullptr, att1_h, (const int*)nullptr);
    // embIH = embg @ WihE_p^T + bsum_p  (M=1280, N=2048 permuted c=4d+g) -> f32
    hipLaunchKernelGGL((gemm_k512<EPI_F32B>), dim3(16, 10), dim3(256), 0, stream,
                       embg, WihE_p, 2048, bsum_p, embIH, (f16*)nullptr, (const int*)nullptr);

    // 20-step recurrence: 64 batches x 4 quarter-blocks, 4-block slot sync
    hipLaunchKernelGGL(k_loop4, dim3(256), dim3(512), 0, stream,
                       att1_h, enc_h, W1q4, BpQ4, embIH, W_fa, b_fa, bcat,
                       lens, cinit, hbuf, alph_out, xatt2, xe, xxa, gsync);

    // predictions = h(1..20) @ W_fc^T + b_fc, masked scatter (XCD-pinned swizzle)
    hipLaunchKernelGGL((gemm_k512<EPI_PREDS>), dim3(2400), dim3(256), 0, stream,
                       hbuf + 32768, Wfc_h, CVP, b_fc, out, (f16*)nullptr, lens);
}

// Round 12
// 546.139 us; speedup vs baseline: 4.7337x; 1.0141x over previous
//
#include <hip/hip_runtime.h>
#include <hip/hip_bf16.h>

typedef _Float16 f16;
typedef __attribute__((ext_vector_type(8))) _Float16 f16x8;
typedef __attribute__((ext_vector_type(2))) _Float16 f16x2;
typedef __attribute__((ext_vector_type(4))) float f32x4;

constexpr int CB = 64, CP = 196, CH = 512, CV = 30000, CVP = 30080, CT = 20;
constexpr int NT = 235;  // preds col tiles

__device__ __forceinline__ float sigf(float x) { return 1.f / (1.f + __expf(-x)); }

#if defined(__has_builtin)
#if __has_builtin(__builtin_amdgcn_fdot2)
#define HAVE_FDOT2 1
#endif
#endif

__device__ __forceinline__ f16x2 asf16x2(unsigned u) {
    union { unsigned x; f16x2 h; } c; c.x = u; return c.h;
}
__device__ __forceinline__ float dotp(f16x2 a, f16x2 b, float c) {
#ifdef HAVE_FDOT2
    return __builtin_amdgcn_fdot2(a, b, c, false);
#else
    return fmaf((float)a[0], (float)b[0], fmaf((float)a[1], (float)b[1], c));
#endif
}

// ---- relaxed agent-scope (sc1, L3-coherent) helpers
__device__ __forceinline__ unsigned ald_u(const unsigned* p) {
    return __hip_atomic_load(p, __ATOMIC_RELAXED, __HIP_MEMORY_SCOPE_AGENT);
}
__device__ __forceinline__ void ast_u(unsigned* p, unsigned v) {
    __hip_atomic_store(p, v, __ATOMIC_RELAXED, __HIP_MEMORY_SCOPE_AGENT);
}
__device__ __forceinline__ float ald_f(const float* p) {
    return __hip_atomic_load(p, __ATOMIC_RELAXED, __HIP_MEMORY_SCOPE_AGENT);
}
__device__ __forceinline__ void ast_f(float* p, float v) {
    __hip_atomic_store(p, v, __ATOMIC_RELAXED, __HIP_MEMORY_SCOPE_AGENT);
}

// ---- 16-producer slot sync (one 64B line per sync point per quad).
// Producer writes own slot (no RMW); consumer lanes poll 16 slots in parallel.
__device__ __forceinline__ void wait16(const int* base, int target) {
    if (threadIdx.x < 64) {
        for (;;) {
            int v = __hip_atomic_load(base + (threadIdx.x & 15), __ATOMIC_RELAXED,
                                      __HIP_MEMORY_SCOPE_AGENT);
            if (__all(v >= target)) break;
            __builtin_amdgcn_s_sleep(1);
        }
    }
    __builtin_amdgcn_s_barrier();
    __builtin_amdgcn_sched_barrier(0);
}
__device__ __forceinline__ void post16(int* slot, int val) {
    __syncthreads();
    if (threadIdx.x == 0)
        __hip_atomic_store(slot, val, __ATOMIC_RELAXED, __HIP_MEMORY_SCOPE_AGENT);
}

// ---------------------------------------------------------------------------
// mega convert/transpose/prep kernel (one-time prologue)
//   W1L[s(16)][kk4(64)][o(64)][8] : global out O=64s+o; O<512 -> att2 dim O
//                                   (W_da); else gate dim O-512 (W_fb)
//   BpL[s(16)][kk4(128)][o(128)][8]: c = 128s+o (c=4d+g); K=[xawe;h] chunk 8kk4
//   WihE_p[c][512]                 : c = 4d+g rows of W_ih cols 0..511
// ---------------------------------------------------------------------------
__device__ __forceinline__ void cvt8(const float* __restrict__ s, f16* __restrict__ d) {
    float4 a = *(const float4*)s;
    float4 b = *(const float4*)(s + 4);
    f16x8 o;
    o[0] = (f16)a.x; o[1] = (f16)a.y; o[2] = (f16)a.z; o[3] = (f16)a.w;
    o[4] = (f16)b.x; o[5] = (f16)b.y; o[6] = (f16)b.z; o[7] = (f16)b.w;
    *(f16x8*)d = o;
}

__global__ __launch_bounds__(256) void k_mega(
    const float* __restrict__ enc, const float* __restrict__ W_ea,
    const float* __restrict__ W_da, const float* __restrict__ W_fb,
    const float* __restrict__ W_ih, const float* __restrict__ W_hh,
    const float* __restrict__ W_fc, const float* __restrict__ emb,
    const int* __restrict__ caps, const float* __restrict__ b_da,
    const float* __restrict__ b_fb, const float* __restrict__ b_ih,
    const float* __restrict__ b_hh,
    f16* __restrict__ enc_h, f16* __restrict__ Wea_h, f16* __restrict__ W1L,
    f16* __restrict__ BpL, f16* __restrict__ WihE_p, f16* __restrict__ Wfc_h,
    f16* __restrict__ embg, float* __restrict__ bcat, float* __restrict__ bsum_p,
    int* __restrict__ gsync)
{
    constexpr long long E0 = 802816;            // enc cvt
    constexpr long long E1 = E0 + 32768;        // W_ea
    constexpr long long E2 = E1 + 1920000;      // W_fc
    constexpr long long E3 = E2 + 5120;         // Wfc pad zeros
    constexpr long long E4 = E3 + 81920;        // emb gather
    constexpr long long E5 = E4 + 65536;        // W1L  (16s x 64kk4 x 64o)
    constexpr long long E6 = E5 + 262144;       // BpL  (16s x 128kk4 x 128o)
    constexpr long long E7 = E6 + 131072;       // WihE_p (2048c x 64)
    constexpr long long E8 = E7 + 3072;         // biases
    constexpr long long TOT = E8 + 1024;        // gsync zero

    for (long long id = (long long)blockIdx.x * 256 + threadIdx.x; id < TOT;
         id += (long long)gridDim.x * 256) {
        if (id < E0) {
            cvt8(enc + id * 8, enc_h + id * 8);
        } else if (id < E1) {
            long long c = id - E0; cvt8(W_ea + c * 8, Wea_h + c * 8);
        } else if (id < E2) {
            long long c = id - E1; cvt8(W_fc + c * 8, Wfc_h + c * 8);
        } else if (id < E3) {
            long long c = id - E2; f16x8 z = {};
            *(f16x8*)&Wfc_h[15360000 + c * 8] = z;
        } else if (id < E4) {
            long long c = id - E3; int m = (int)(c >> 6), j = (int)(c & 63);
            int tt = m >> 6, bb = m & 63;
            int row = caps[bb * 21 + tt];
            cvt8(emb + (size_t)row * 512 + j * 8, embg + (size_t)m * 512 + j * 8);
        } else if (id < E5) {
            long long c = id - E4;
            int o = (int)(c & 63), kk4 = (int)((c >> 6) & 63), s = (int)(c >> 12);
            int O = 64 * s + o;
            const float* src = (O < 512) ? &W_da[(size_t)O * 512]
                                         : &W_fb[(size_t)(O - 512) * 512];
            cvt8(src + kk4 * 8, &W1L[(((size_t)s * 64 + kk4) * 64 + o) * 8]);
        } else if (id < E6) {
            long long c = id - E5;
            int o = (int)(c & 127), kk4 = (int)((c >> 7) & 127), s = (int)(c >> 14);
            int d = 32 * s + (o >> 2), g = o & 3;
            int r = g * 512 + d;
            const float* src = (kk4 < 64) ? &W_ih[(size_t)r * 1024 + 512 + kk4 * 8]
                                          : &W_hh[(size_t)r * 512 + (kk4 - 64) * 8];
            cvt8(src, &BpL[(((size_t)s * 128 + kk4) * 128 + o) * 8]);
        } else if (id < E7) {
            long long c = id - E6;
            int cc = (int)(c >> 6), j8 = (int)(c & 63);
            int r = (cc & 3) * 512 + (cc >> 2);
            cvt8(W_ih + (size_t)r * 1024 + j8 * 8, WihE_p + (size_t)cc * 512 + j8 * 8);
        } else if (id < E8) {
            int i = (int)(id - E7);
            if (i < 512) bcat[i] = b_da[i];
            else if (i < 1024) bcat[i] = b_fb[i - 512];
            else {
                int cc = i - 1024;
                int r = (cc & 3) * 512 + (cc >> 2);
                bsum_p[cc] = b_ih[r] + b_hh[r];
            }
        } else {
            gsync[(int)(id - E8)] = 0;
        }
    }
}

// h0 = mean_p(enc) -> hbuf slot 0 (f16) and cinit (f32)
__global__ __launch_bounds__(256) void k_h0(const float* __restrict__ enc,
                                            f16* __restrict__ hbuf, float* __restrict__ cinit)
{
    int b = blockIdx.x;
    for (int h = threadIdx.x; h < CH; h += 256) {
        const float* p = enc + (size_t)b * CP * CH + h;
        float s = 0.f;
        for (int q = 0; q < CP; ++q) s += p[q * CH];
        s *= (1.f / 196.f);
        hbuf[b * CH + h] = (f16)s;
        cinit[b * CH + h] = s;
    }
}

// ---------------------------------------------------------------------------
// K=512 GEMM: tile 128x128, BK=32, padded LDS, reg prefetch.
// EPI_PREDS: 1-D grid 2400 with XCD-pinning swizzle (B tile L2-resident).
// ---------------------------------------------------------------------------
enum { EPI_F16B = 0, EPI_F32B = 1, EPI_PREDS = 2 };

template <int EPI>
__global__ __launch_bounds__(256) void gemm_k512(
    const f16* __restrict__ Aptr, const f16* __restrict__ Bptr, int N,
    const float* __restrict__ bias, float* __restrict__ Cf,
    f16* __restrict__ Ch, const int* __restrict__ lengths)
{
    constexpr int LD = 40;
    const int tid = threadIdx.x;
    const int lane = tid & 63, wave = tid >> 6;
    const int wr = wave >> 1, wc = wave & 1;
    int bx, by;
    if constexpr (EPI == EPI_PREDS) {
        int bid1 = blockIdx.x;
        int nt = (bid1 / 80) * 8 + (bid1 & 7);
        int mt = (bid1 >> 3) % 10;
        if (nt >= NT) return;
        bx = nt; by = mt;
    } else {
        bx = blockIdx.x; by = blockIdx.y;
    }

    __shared__ f16 As[128 * LD];
    __shared__ f16 Bs[128 * LD];

    const f16* Ag = Aptr + (size_t)by * 128 * 512;
    const f16* Bg = Bptr + (size_t)bx * 128 * 512;

    int srow[2], skc[2];
#pragma unroll
    for (int i = 0; i < 2; ++i) { int ci = tid + i * 256; srow[i] = ci >> 2; skc[i] = (ci & 3) * 8; }

    f32x4 acc[4][4] = {};
    f16x8 ar[2], br[2];
#pragma unroll
    for (int i = 0; i < 2; ++i) {
        ar[i] = *(const f16x8*)&Ag[(size_t)srow[i] * 512 + skc[i]];
        br[i] = *(const f16x8*)&Bg[(size_t)srow[i] * 512 + skc[i]];
    }

    const int rr = lane & 15, kg = (lane >> 4) * 8;
    for (int kt = 0; kt < 16; ++kt) {
        __syncthreads();
#pragma unroll
        for (int i = 0; i < 2; ++i) {
            *(f16x8*)&As[srow[i] * LD + skc[i]] = ar[i];
            *(f16x8*)&Bs[srow[i] * LD + skc[i]] = br[i];
        }
        __syncthreads();
        if (kt < 15) {
            int k0 = (kt + 1) * 32;
#pragma unroll
            for (int i = 0; i < 2; ++i) {
                ar[i] = *(const f16x8*)&Ag[(size_t)srow[i] * 512 + k0 + skc[i]];
                br[i] = *(const f16x8*)&Bg[(size_t)srow[i] * 512 + k0 + skc[i]];
            }
        }
        f16x8 af[4], bf[4];
#pragma unroll
        for (int mi = 0; mi < 4; ++mi) af[mi] = *(const f16x8*)&As[(wr * 64 + mi * 16 + rr) * LD + kg];
#pragma unroll
        for (int ni = 0; ni < 4; ++ni) bf[ni] = *(const f16x8*)&Bs[(wc * 64 + ni * 16 + rr) * LD + kg];
#pragma unroll
        for (int mi = 0; mi < 4; ++mi)
#pragma unroll
            for (int ni = 0; ni < 4; ++ni)
                acc[mi][ni] = __builtin_amdgcn_mfma_f32_16x16x32_f16(af[mi], bf[ni], acc[mi][ni], 0, 0, 0);
    }

    const int m0 = by * 128 + wr * 64;
    const int n0 = bx * 128 + wc * 64;
    const int r0 = (lane >> 4) * 4, cc = lane & 15;
#pragma unroll
    for (int mi = 0; mi < 4; ++mi) {
#pragma unroll
        for (int ni = 0; ni < 4; ++ni) {
#pragma unroll
            for (int r = 0; r < 4; ++r) {
                int m = m0 + mi * 16 + r0 + r;
                int n = n0 + ni * 16 + cc;
                float v = acc[mi][ni][r];
                if constexpr (EPI == EPI_F16B) {
                    Ch[(size_t)m * N + n] = (f16)(v + bias[n]);
                } else if constexpr (EPI == EPI_F32B) {
                    Cf[(size_t)m * N + n] = v + bias[n];
                } else {
                    if (n < CV) {
                        int tt = m >> 6, b = m & 63;
                        float val = ((lengths[b] - 1) > tt) ? (v + bias[n]) : 0.f;
                        __builtin_nontemporal_store(val, &Cf[(size_t)b * (CT * CV) + (size_t)tt * CV + n]);
                    }
                }
            }
        }
    }
}

// ---------------------------------------------------------------------------
// Recurrence: 256 blocks = 16 quads (4 batches) x 16 out-slices, 512 threads.
// Each weight load feeds 4 batches (weight L2 traffic /4 vs r11).
// bid = q4*16 + s -> slice s pinned to XCD s%8 (per-XCD weights ~640KB).
// Attention role: batt = 4q4 + (s&3), q = s>>2 (unchanged per-block cost).
// Sync: 4 points/step, 16 slots each (one 64B line per point per quad).
// ---------------------------------------------------------------------------
__global__ __launch_bounds__(512) void k_loopQ(
    const f16* __restrict__ att1, const f16* __restrict__ ench,
    const f16* __restrict__ W1L, const f16* __restrict__ BpL,
    const float* __restrict__ embIH, const float* __restrict__ Wfa,
    const float* __restrict__ bfa, const float* __restrict__ bcat,
    const int* __restrict__ lens, const float* __restrict__ cinit,
    f16* __restrict__ hbuf, float* __restrict__ alph,
    float* __restrict__ xatt2, float* __restrict__ xe,
    float* __restrict__ xxa, int* __restrict__ gsync)
{
    const int bid = blockIdx.x, tid = threadIdx.x;
    const int lane = tid & 63, wv = tid >> 6;
    const int q4 = bid >> 4, s = bid & 15;
    const int b0 = 4 * q4;
    const int batt = b0 + (s & 3), q = s >> 2;

    int* sl = gsync + q4 * 64;  // [s1|s2|s3|s4] x 16 ints

    __shared__ __align__(16) f16 h_s[4 * 512];
    __shared__ __align__(16) float part[2048];
    __shared__ float a2f[512], ga_s[128];
    __shared__ float es[196], als[196], red[16];
    __shared__ float awp[32][128];
    __shared__ __align__(16) f16 xh_s[4 * 1024];
    __shared__ float gt[512];
    __shared__ f16 htmp[128];
    __shared__ float c_s[128];

    ((unsigned*)h_s)[tid] = ((const unsigned*)(hbuf + b0 * 512))[tid];
    ((unsigned*)h_s)[tid + 512] = ((const unsigned*)(hbuf + b0 * 512))[tid + 512];
    if (tid < 128) c_s[tid] = cinit[(b0 + (tid >> 5)) * 512 + 32 * s + (tid & 31)];

    const float bfa0 = bfa[0];
    const int lb = lens[batt];
    float wfr[8];
#pragma unroll
    for (int j = 0; j < 8; ++j) wfr[j] = Wfa[lane * 8 + j];
    const int ecnt = (56 - wv) >> 3;
    const int ar_ = lane >> 4, ac_ = lane & 15;
    const int ks1 = tid >> 6, o1 = tid & 63;     // phase1: K-split 8 x 64 outs
    const int ks4 = tid >> 7, o4 = tid & 127;    // phase4: K-split 4 x 128 outs
    __syncthreads();

    for (int t = 0; t < CT; ++t) {
        if (t > 0) {
            wait16(sl + 48, t);
            const unsigned* hp = (const unsigned*)(hbuf + (size_t)t * 32768 + b0 * 512);
            ((unsigned*)h_s)[tid] = ald_u(hp + tid);
            ((unsigned*)h_s)[tid + 512] = ald_u(hp + tid + 512);
            __syncthreads();
        }

        // ---- phase 1: att2+gate outs [64s,64s+64) x 4 batches (K-split 8) ----
        {
            const f16* wp = W1L + (((size_t)s * 64 + ks1 * 8) * 64 + o1) * 8;
            const uint4* xq = (const uint4*)h_s;
            float a0 = 0.f, a1 = 0.f, a2 = 0.f, a3 = 0.f;
#pragma unroll 4
            for (int i = 0; i < 8; ++i) {
                uint4 w = *(const uint4*)(wp + (size_t)i * 512);
                int kk4 = ks1 * 8 + i;
                uint4 x0 = xq[kk4], x1 = xq[64 + kk4], x2 = xq[128 + kk4], x3 = xq[192 + kk4];
                a0 = dotp(asf16x2(w.x), asf16x2(x0.x), a0);
                a1 = dotp(asf16x2(w.x), asf16x2(x1.x), a1);
                a2 = dotp(asf16x2(w.x), asf16x2(x2.x), a2);
                a3 = dotp(asf16x2(w.x), asf16x2(x3.x), a3);
                a0 = dotp(asf16x2(w.y), asf16x2(x0.y), a0);
                a1 = dotp(asf16x2(w.y), asf16x2(x1.y), a1);
                a2 = dotp(asf16x2(w.y), asf16x2(x2.y), a2);
                a3 = dotp(asf16x2(w.y), asf16x2(x3.y), a3);
                a0 = dotp(asf16x2(w.z), asf16x2(x0.z), a0);
                a1 = dotp(asf16x2(w.z), asf16x2(x1.z), a1);
                a2 = dotp(asf16x2(w.z), asf16x2(x2.z), a2);
                a3 = dotp(asf16x2(w.z), asf16x2(x3.z), a3);
                a0 = dotp(asf16x2(w.w), asf16x2(x0.w), a0);
                a1 = dotp(asf16x2(w.w), asf16x2(x1.w), a1);
                a2 = dotp(asf16x2(w.w), asf16x2(x2.w), a2);
                a3 = dotp(asf16x2(w.w), asf16x2(x3.w), a3);
            }
            f32x4 pk; pk[0] = a0; pk[1] = a1; pk[2] = a2; pk[3] = a3;
            *(f32x4*)&part[ks1 * 256 + o1 * 4] = pk;
        }
        __syncthreads();
        if (tid < 256) {
            float v = 0.f;
#pragma unroll
            for (int w8 = 0; w8 < 8; ++w8) v += part[w8 * 256 + tid];
            int o = tid >> 2, bb = tid & 3;
            int O = 64 * s + o;
            ast_f(&xatt2[(size_t)(b0 + bb) * 1024 + O], v + bcat[O]);
        }

        // prefetch att1 e-row fragments (overlaps s1 sync)
        f16x8 fr[7];
#pragma unroll
        for (int i = 0; i < 7; ++i)
            if (i < ecnt)
                fr[i] = *(const f16x8*)&att1[((size_t)batt * CP + 49 * q + wv + 8 * i) * 512 + lane * 8];

        post16(sl + s, t + 1);
        wait16(sl, t + 1);
        a2f[tid] = ald_f(&xatt2[(size_t)batt * 1024 + tid]);
        if (tid < 128) ga_s[tid] = ald_f(&xatt2[(size_t)batt * 1024 + 512 + 128 * q + tid]);
        __syncthreads();

        // ---- phase 2: e rows [49q, 49q+49) ----
        {
            float a2r[8];
#pragma unroll
            for (int j = 0; j < 8; ++j) a2r[j] = a2f[lane * 8 + j];
#pragma unroll
            for (int i = 0; i < 7; ++i)
                if (i < ecnt) {
                    float e = 0.f;
#pragma unroll
                    for (int j = 0; j < 8; ++j)
                        e += fmaxf((float)fr[i][j] + a2r[j], 0.f) * wfr[j];
#pragma unroll
                    for (int o = 32; o; o >>= 1) e += __shfl_down(e, o);
                    if (lane == 0) ast_f(&xe[batt * 196 + 49 * q + wv + 8 * i], e + bfa0);
                }
        }

        // prefetch enc awe fragments (overlaps s2 sync)
        f16x8 er[7];
#pragma unroll
        for (int it = 0; it < 7; ++it) {
            int p = it * 32 + wv * 4 + ar_;
            if (p < CP)
                er[it] = *(const f16x8*)&ench[((size_t)batt * CP + p) * 512 + 128 * q + ac_ * 8];
        }

        post16(sl + 16 + s, t + 1);
        wait16(sl + 16, t + 1);
        if (tid < CP) es[tid] = ald_f(&xe[batt * 196 + tid]);
        __syncthreads();

        // ---- phase 3: softmax (replicated) + awe h-slice + xawe ----
        {
            float ev = (tid < CP) ? es[tid] : -1e30f;
            float mx = ev;
#pragma unroll
            for (int o = 32; o; o >>= 1) mx = fmaxf(mx, __shfl_down(mx, o));
            if (lane == 0) red[wv] = mx;
            __syncthreads();
            mx = red[0];
#pragma unroll
            for (int w = 1; w < 8; ++w) mx = fmaxf(mx, red[w]);
            float ex = (tid < CP) ? __expf(ev - mx) : 0.f;
            float sm = ex;
#pragma unroll
            for (int o = 32; o; o >>= 1) sm += __shfl_down(sm, o);
            if (lane == 0) red[8 + wv] = sm;
            __syncthreads();
            sm = red[8];
#pragma unroll
            for (int w = 1; w < 8; ++w) sm += red[8 + w];
            float al = ex / sm;
            if (tid < CP) {
                als[tid] = al;
                if (tid >= 49 * q && tid < 49 * (q + 1))
                    alph[(size_t)batt * (CT * CP) + t * CP + tid] = ((lb - 1) > t) ? al : 0.f;
            }
        }
        __syncthreads();
        {
            float aw[8] = {};
#pragma unroll
            for (int it = 0; it < 7; ++it) {
                int p = it * 32 + wv * 4 + ar_;
                if (p < CP) {
                    float a = als[p];
#pragma unroll
                    for (int j = 0; j < 8; ++j) aw[j] = fmaf(a, (float)er[it][j], aw[j]);
                }
            }
#pragma unroll
            for (int j = 0; j < 8; ++j) awp[wv * 4 + ar_][ac_ * 8 + j] = aw[j];
        }
        __syncthreads();
        if (tid < 128) {
            float sv = 0.f;
#pragma unroll
            for (int g = 0; g < 32; ++g) sv += awp[g][tid];
            ast_f(&xxa[batt * 512 + 128 * q + tid], sigf(ga_s[tid]) * sv);
        }
        post16(sl + 32 + s, t + 1);
        wait16(sl + 32, t + 1);
        // build xh_s[4][1024] = [xawe; h] per batch
#pragma unroll
        for (int k = 0; k < 4; ++k) {
            int c4 = k * 512 + tid;
            int bb = c4 >> 9, j = c4 & 511;
            xh_s[bb * 1024 + j] = (f16)ald_f(&xxa[(b0 + bb) * 512 + j]);
        }
#pragma unroll
        for (int k = 0; k < 2; ++k) {
            int u = k * 512 + tid;
            int bb = u >> 8, jj = u & 255;
            ((unsigned*)xh_s)[bb * 512 + 256 + jj] = ((unsigned*)h_s)[bb * 256 + jj];
        }
        __syncthreads();

        // ---- phase 4: gates c=[128s,128s+128) x 4 batches (K-split 4) ----
        {
            const f16* wp = BpL + (((size_t)s * 128 + ks4 * 32) * 128 + o4) * 8;
            const uint4* xq = (const uint4*)xh_s;
            float a0 = 0.f, a1 = 0.f, a2 = 0.f, a3 = 0.f;
#pragma unroll 4
            for (int i = 0; i < 32; ++i) {
                uint4 w = *(const uint4*)(wp + (size_t)i * 1024);
                int kk4 = ks4 * 32 + i;
                uint4 x0 = xq[kk4], x1 = xq[128 + kk4], x2 = xq[256 + kk4], x3 = xq[384 + kk4];
                a0 = dotp(asf16x2(w.x), asf16x2(x0.x), a0);
                a1 = dotp(asf16x2(w.x), asf16x2(x1.x), a1);
                a2 = dotp(asf16x2(w.x), asf16x2(x2.x), a2);
                a3 = dotp(asf16x2(w.x), asf16x2(x3.x), a3);
                a0 = dotp(asf16x2(w.y), asf16x2(x0.y), a0);
                a1 = dotp(asf16x2(w.y), asf16x2(x1.y), a1);
                a2 = dotp(asf16x2(w.y), asf16x2(x2.y), a2);
                a3 = dotp(asf16x2(w.y), asf16x2(x3.y), a3);
                a0 = dotp(asf16x2(w.z), asf16x2(x0.z), a0);
                a1 = dotp(asf16x2(w.z), asf16x2(x1.z), a1);
                a2 = dotp(asf16x2(w.z), asf16x2(x2.z), a2);
                a3 = dotp(asf16x2(w.z), asf16x2(x3.z), a3);
                a0 = dotp(asf16x2(w.w), asf16x2(x0.w), a0);
                a1 = dotp(asf16x2(w.w), asf16x2(x1.w), a1);
                a2 = dotp(asf16x2(w.w), asf16x2(x2.w), a2);
                a3 = dotp(asf16x2(w.w), asf16x2(x3.w), a3);
            }
            f32x4 pk; pk[0] = a0; pk[1] = a1; pk[2] = a2; pk[3] = a3;
            *(f32x4*)&part[ks4 * 512 + o4 * 4] = pk;
        }
        __syncthreads();
        {
            float g = part[tid] + part[512 + tid] + part[1024 + tid] + part[1536 + tid];
            int o = tid >> 2, bb = tid & 3;
            gt[tid] = g + embIH[(size_t)(t * 64 + b0 + bb) * 2048 + 128 * s + o];
        }
        __syncthreads();
        if (tid < 128) {
            int dd = tid >> 2, bb = tid & 3;
            float gi = gt[(4 * dd + 0) * 4 + bb];
            float gf = gt[(4 * dd + 1) * 4 + bb];
            float gg = gt[(4 * dd + 2) * 4 + bb];
            float go = gt[(4 * dd + 3) * 4 + bb];
            float cn = sigf(gf) * c_s[bb * 32 + dd] + sigf(gi) * tanhf(gg);
            c_s[bb * 32 + dd] = cn;
            htmp[bb * 32 + dd] = (f16)(sigf(go) * tanhf(cn));
        }
        __syncthreads();
        if (tid < 64) {
            int bb = tid >> 4, dd2 = (tid & 15) * 2;
            union { f16 h[2]; unsigned u; } pk;
            pk.h[0] = htmp[bb * 32 + dd2]; pk.h[1] = htmp[bb * 32 + dd2 + 1];
            size_t off = (size_t)(t + 1) * 32768 + (b0 + bb) * 512 + 32 * s + dd2;
            ast_u((unsigned*)hbuf + (off >> 1), pk.u);
        }
        post16(sl + 48 + s, t + 1);
    }
}

// ---------------------------------------------------------------------------
extern "C" void kernel_launch(void* const* d_in, const int* in_sizes, int n_in,
                              void* d_out, int out_size, void* d_ws, size_t ws_size,
                              hipStream_t stream)
{
    const float* enc  = (const float*)d_in[0];
    const int*   caps = (const int*)d_in[1];
    const int*   lens = (const int*)d_in[2];
    const float* emb  = (const float*)d_in[3];
    const float* W_ea = (const float*)d_in[4];
    const float* b_ea = (const float*)d_in[5];
    const float* W_da = (const float*)d_in[6];
    const float* b_da = (const float*)d_in[7];
    const float* W_fa = (const float*)d_in[8];
    const float* b_fa = (const float*)d_in[9];
    const float* W_fb = (const float*)d_in[10];
    const float* b_fb = (const float*)d_in[11];
    const float* W_ih = (const float*)d_in[12];
    const float* W_hh = (const float*)d_in[13];
    const float* b_ih = (const float*)d_in[14];
    const float* b_hh = (const float*)d_in[15];
    const float* W_fc = (const float*)d_in[16];
    const float* b_fc = (const float*)d_in[17];

    float* out = (float*)d_out;
    float* alph_out = out + (size_t)CB * CT * CV;

    char* p = (char*)d_ws;
    auto carve = [&](size_t bytes) {
        char* r = p;
        p += (bytes + 255) & ~(size_t)255;
        return r;
    };
    f16* enc_h   = (f16*)carve((size_t)12544 * 512 * 2);
    f16* att1_h  = (f16*)carve((size_t)12544 * 512 * 2);
    f16* Wea_h   = (f16*)carve((size_t)512 * 512 * 2);
    f16* W1L     = (f16*)carve((size_t)16 * 64 * 64 * 8 * 2);    // 1 MB
    f16* BpL     = (f16*)carve((size_t)16 * 128 * 128 * 8 * 2);  // 4 MB
    f16* WihE_p  = (f16*)carve((size_t)2048 * 512 * 2);
    f16* Wfc_h   = (f16*)carve((size_t)CVP * 512 * 2);
    f16* embg    = (f16*)carve((size_t)1280 * 512 * 2);
    float* embIH = (float*)carve((size_t)1280 * 2048 * 4);
    float* bcat  = (float*)carve(1024 * 4);
    float* bsum_p= (float*)carve(2048 * 4);
    f16* hbuf    = (f16*)carve((size_t)21 * 64 * 512 * 2);
    float* cinit = (float*)carve((size_t)64 * 512 * 4);
    float* xatt2 = (float*)carve((size_t)64 * 1024 * 4);
    float* xe    = (float*)carve((size_t)64 * 196 * 4);
    float* xxa   = (float*)carve((size_t)64 * 512 * 4);
    int* gsync   = (int*)carve(1024 * 4);

    hipLaunchKernelGGL(k_mega, dim3(4096), dim3(256), 0, stream,
                       enc, W_ea, W_da, W_fb, W_ih, W_hh, W_fc, emb, caps,
                       b_da, b_fb, b_ih, b_hh,
                       enc_h, Wea_h, W1L, BpL, WihE_p, Wfc_h, embg, bcat, bsum_p, gsync);

    hipLaunchKernelGGL(k_h0, dim3(64), dim3(256), 0, stream, enc, hbuf, cinit);

    // att1 = enc_h @ W_ea^T + b_ea  (M=12544, N=512) -> f16
    hipLaunchKernelGGL((gemm_k512<EPI_F16B>), dim3(4, 98), dim3(256), 0, stream,
                       enc_h, Wea_h, 512, b_ea, (float*)nullptr, att1_h, (const int*)nullptr);
    // embIH = embg @ WihE_p^T + bsum_p  (M=1280, N=2048 permuted c=4d+g) -> f32
    hipLaunchKernelGGL((gemm_k512<EPI_F32B>), dim3(16, 10), dim3(256), 0, stream,
                       embg, WihE_p, 2048, bsum_p, embIH, (f16*)nullptr, (const int*)nullptr);

    // 20-step recurrence: 16 quads x 16 slices, 16-slot slot sync
    hipLaunchKernelGGL(k_loopQ, dim3(256), dim3(512), 0, stream,
                       att1_h, enc_h, W1L, BpL, embIH, W_fa, b_fa, bcat,
                       lens, cinit, hbuf, alph_out, xatt2, xe, xxa, gsync);

    // predictions = h(1..20) @ W_fc^T + b_fc, masked scatter (XCD-pinned swizzle)
    hipLaunchKernelGGL((gemm_k512<EPI_PREDS>), dim3(2400), dim3(256), 0, stream,
                       hbuf + 32768, Wfc_h, CVP, b_fc, out, (f16*)nullptr, lens);
}